// Round 15
// baseline (1395.651 us; speedup 1.0000x reference)
//
#include <hip/hip_runtime.h>
#include <cstdint>
#include <cstddef>
#include <type_traits>

#define NN 16384
#define EE 49152
#define BB 256
// D=256, G=16, 16 channels per group, HD=16

typedef _Float16 f16;
typedef _Float16 half8 __attribute__((ext_vector_type(8)));
typedef _Float16 half4v __attribute__((ext_vector_type(4)));
typedef _Float16 half2v __attribute__((ext_vector_type(2)));
typedef float floatx4 __attribute__((ext_vector_type(4)));

#if defined(__has_builtin)
#if __has_builtin(__builtin_amdgcn_fdot2)
#define HAVE_FDOT2 1
#endif
#endif

static constexpr size_t ND = (size_t)NN * 256;

// ---------------- setup kernels ----------------

__global__ __launch_bounds__(256) void count_deg_kernel(const int* __restrict__ dst, int* __restrict__ cnt, int e) {
  int i = blockIdx.x * 256 + threadIdx.x;
  if (i < e) atomicAdd(&cnt[dst[i]], 1);
}
__global__ __launch_bounds__(256) void clip_deg_kernel(const int* __restrict__ cnt, int* __restrict__ deg, int n) {
  int i = blockIdx.x * 256 + threadIdx.x;
  if (i < n) { int v = cnt[i] - 1; deg[i] = v < 0 ? 0 : (v > 3 ? 3 : v); }
}
__global__ __launch_bounds__(256) void goff_kernel(const int* __restrict__ batch, int* __restrict__ goff, int n, int b) {
  int i = blockIdx.x * 256 + threadIdx.x;
  if (i > n) return;
  int cur = (i < n) ? batch[i] : b;
  int prev = (i == 0) ? -1 : batch[i - 1];
  for (int x = prev + 1; x <= cur; x++) goff[x] = i;
}
__global__ __launch_bounds__(256) void scan_off_kernel(const int* __restrict__ cnt, int* __restrict__ off) {
  __shared__ int part[256];
  int tid = threadIdx.x;
  int base = tid * 64;
  int s = 0;
  for (int i = 0; i < 64; i++) s += cnt[base + i];
  part[tid] = s;
  __syncthreads();
  for (int o = 1; o < 256; o <<= 1) {
    int t = (tid >= o) ? part[tid - o] : 0;
    __syncthreads();
    part[tid] += t;
    __syncthreads();
  }
  int run = (tid == 0) ? 0 : part[tid - 1];
  for (int i = 0; i < 64; i++) {
    off[base + i] = run;
    run += cnt[base + i];
  }
  if (tid == 255) off[NN] = run;
}
__global__ __launch_bounds__(256) void copy_i_kernel(const int* __restrict__ a, int* __restrict__ b, int n) {
  int i = blockIdx.x * 256 + threadIdx.x;
  if (i < n) b[i] = a[i];
}
__global__ __launch_bounds__(256) void fill_elist_kernel(const int* __restrict__ dst,
    int* __restrict__ cursor, int* __restrict__ elist, int e) {
  int i = blockIdx.x * 256 + threadIdx.x;
  if (i < e) {
    int p = atomicAdd(&cursor[dst[i]], 1);
    elist[p] = i;
  }
}
// gather edge data into CSR (dst-sorted) order
__global__ __launch_bounds__(256) void gather_edges_kernel(const int* __restrict__ elist,
    const int* __restrict__ eattr, const int* __restrict__ src, const int* __restrict__ dst,
    const float* __restrict__ edist, int* __restrict__ ea_s, int* __restrict__ src_s,
    float* __restrict__ ed_s) {
  int j = blockIdx.x * 256 + threadIdx.x;
  if (j >= EE) return;
  int e = elist[j];
  ea_s[j * 3 + 0] = eattr[e * 3 + 0];
  ea_s[j * 3 + 1] = eattr[e * 3 + 1];
  ea_s[j * 3 + 2] = eattr[e * 3 + 2];
  src_s[j] = src[e];
  ed_s[j] = edist[e];
}
// dstH = f16(a + b)
__global__ __launch_bounds__(256) void add3h_kernel(f16* __restrict__ dstH,
    const float* __restrict__ a, const float* __restrict__ b, int n4) {
  int i = blockIdx.x * 256 + threadIdx.x;
  if (i >= n4) return;
  float4 x = reinterpret_cast<const float4*>(a)[i];
  float4 y = reinterpret_cast<const float4*>(b)[i];
  half4v h;
  h[0] = (f16)(x.x + y.x); h[1] = (f16)(x.y + y.y);
  h[2] = (f16)(x.z + y.z); h[3] = (f16)(x.w + y.w);
  reinterpret_cast<half4v*>(dstH)[i] = h;
}
__global__ __launch_bounds__(256) void f2h_kernel(const float* __restrict__ in, f16* __restrict__ out, int n4) {
  int i = blockIdx.x * 256 + threadIdx.x;
  if (i >= n4) return;
  float4 v = reinterpret_cast<const float4*>(in)[i];
  half4v o;
  o[0] = (f16)v.x; o[1] = (f16)v.y; o[2] = (f16)v.z; o[3] = (f16)v.w;
  reinterpret_cast<half4v*>(out)[i] = o;
}

// ---------------- segment reduce over CONTIGUOUS CSR rows (init features) ----------------
__global__ __launch_bounds__(256) void seg_reduce_f_kernel(const f16* __restrict__ msg,
    const int* __restrict__ off, float* __restrict__ out) {
  int idx = blockIdx.x * 256 + threadIdx.x;
  int n = idx >> 6, c0 = (idx & 63) * 4;
  int j0 = off[n], j1 = off[n + 1];
  float a0 = 0.f, a1 = 0.f, a2 = 0.f, a3 = 0.f;
  for (int j = j0; j < j1; j++) {
    half4v m0 = *reinterpret_cast<const half4v*>(&msg[(size_t)j * 256 + c0]);
    a0 += (float)m0[0]; a1 += (float)m0[1]; a2 += (float)m0[2]; a3 += (float)m0[3];
  }
  float4 o = {a0, a1, a2, a3};
  *reinterpret_cast<float4*>(&out[(size_t)n * 256 + c0]) = o;
}

// ---------------- initial edge / node features (CSR order) ----------------

__global__ __launch_bounds__(256) void edge_feat_kernel(
    const int* __restrict__ ea_s, const float* __restrict__ ed_s,
    const float* __restrict__ bond2d, const float* __restrict__ gmeans,
    const float* __restrict__ gstds, const float* __restrict__ attn_w,
    const float* __restrict__ attn_b, f16* __restrict__ msg) {
  int lane = threadIdx.x & 63;
  int j = blockIdx.x * 4 + (threadIdx.x >> 6);
  if (j >= EE) return;
  int a0 = ea_s[j * 3 + 0], a1 = ea_s[j * 3 + 1], a2 = ea_s[j * 3 + 2];
  float dist = ed_s[j];
  const float SQ2PI = sqrtf(2.0f * 3.14159f);
  int c0 = lane * 4;
  float4 b0 = *reinterpret_cast<const float4*>(&bond2d[a0 * 256 + c0]);
  float4 b1 = *reinterpret_cast<const float4*>(&bond2d[2048 + a1 * 256 + c0]);
  float4 b2 = *reinterpret_cast<const float4*>(&bond2d[4096 + a2 * 256 + c0]);
  float4 gm = *reinterpret_cast<const float4*>(&gmeans[c0]);
  float4 gs = *reinterpret_cast<const float4*>(&gstds[c0]);
  float4 w2 = *reinterpret_cast<const float4*>(&attn_w[c0]);
  float4 w3 = *reinterpret_cast<const float4*>(&attn_w[256 + c0]);
  float h2[4], h3[4];
  float part = 0.f;
#pragma unroll
  for (int i = 0; i < 4; i++) {
    h2[i] = (&b0.x)[i] + (&b1.x)[i] + (&b2.x)[i];
    float sd = fabsf((&gs.x)[i]) + 0.01f;
    float df = (dist - (&gm.x)[i]) / sd;
    h3[i] = expf(-0.5f * df * df) / (SQ2PI * sd);
    part += (&w2.x)[i] * h2[i] + (&w3.x)[i] * h3[i];
  }
#pragma unroll
  for (int off = 32; off > 0; off >>= 1) part += __shfl_xor(part, off);
  float wg = 1.f / (1.f + expf(-(part + attn_b[0])));
  half4v o;
#pragma unroll
  for (int i = 0; i < 4; i++) o[i] = (f16)(wg * h2[i] + (1.f - wg) * h3[i]);
  *reinterpret_cast<half4v*>(&msg[(size_t)j * 256 + c0]) = o;
}

__global__ __launch_bounds__(256) void atom_finish_kernel(
    const int* __restrict__ xf, const float* __restrict__ emb,
    const float* __restrict__ scale_both, const int* __restrict__ deg,
    const float* __restrict__ tmp, float* __restrict__ h_in, f16* __restrict__ h_inH) {
  int idx = blockIdx.x * 256 + threadIdx.x;
  int n = idx >> 6, c = (idx & 63) * 4;
  float a0 = 0.f, a1 = 0.f, a2 = 0.f, a3 = 0.f;
#pragma unroll
  for (int f = 0; f < 9; f++) {
    int v = xf[n * 9 + f];
    float4 e = *reinterpret_cast<const float4*>(&emb[((size_t)(f * 128 + v)) * 256 + c]);
    a0 += e.x; a1 += e.y; a2 += e.z; a3 += e.w;
  }
  int dg = deg[n];
  float4 s = *reinterpret_cast<const float4*>(&scale_both[dg * 256 + c]);
  float4 t = *reinterpret_cast<const float4*>(&tmp[(size_t)n * 256 + c]);
  float4 r;
  r.x = a0 + expf(s.x) * t.x; r.y = a1 + expf(s.y) * t.y;
  r.z = a2 + expf(s.z) * t.z; r.w = a3 + expf(s.w) * t.w;
  *reinterpret_cast<float4*>(&h_in[(size_t)n * 256 + c]) = r;
  half4v h;
  h[0] = (f16)r.x; h[1] = (f16)r.y; h[2] = (f16)r.z; h[3] = (f16)r.w;
  *reinterpret_cast<half4v*>(&h_inH[(size_t)n * 256 + c]) = h;
}

// ---------------- fp16 MFMA GEMM, tile 128x64, 4 waves (2x2), BK=32, reg prefetch ----------------
// MODE 0: v=acc(+bias); C?=v; Cf?=f16(v)
// MODE 4: v=acc+cnt[row]*bias[col]; Cadd[oi]+=expf(scale[deg[row]*256+col])*v; Cf?=f16(v)
// MODE 5: like 4 but Cadd[oi]= (init store)
// MODE 6: v=acc+bias; GroupNorm per 16-col group (16-lane shuffles); C?=gn; Cf?=f16(gn)
// MODE 7: v=acc+bias; nv=C[oi]+Cadd[oi] + expf(vs2[col])*vout2[batch2[row]*256+col] + expf(scale[col])*v; Cf=f16(nv)
template <int MODE>
__global__ __launch_bounds__(256) void hgemm_kernel(
    const f16* __restrict__ A, const f16* __restrict__ W,
    const float* __restrict__ bias, const float* __restrict__ scale,
    const int* __restrict__ cnt, const int* __restrict__ deg,
    float* __restrict__ C, float* __restrict__ Cadd, f16* __restrict__ Cf,
    const float* __restrict__ vs2, const float* __restrict__ vout2,
    const int* __restrict__ batch2, int K) {
  __shared__ f16 Ah[128 * 40];
  __shared__ f16 Wh[64 * 40];
  const int tid = threadIdx.x;
  const int row0 = blockIdx.x * 128, col0 = blockIdx.y * 64;
  const int lane = tid & 63;
  const int wave = tid >> 6;
  const int wr = (wave >> 1) * 64, wc = (wave & 1) * 32;
  const floatx4 fz = {0.f, 0.f, 0.f, 0.f};
  floatx4 acc[4][2];
#pragma unroll
  for (int m = 0; m < 4; m++)
#pragma unroll
    for (int n = 0; n < 2; n++) acc[m][n] = fz;
  const int q0 = tid * 2;
  const int rA0 = q0 >> 2, pA0 = q0 & 3;
  const int rA1 = (q0 + 1) >> 2, pA1 = (q0 + 1) & 3;
  const int rW = tid >> 2, pW = tid & 3;
  const int kb = (lane >> 4) * 8;
  const int fr = lane & 15;
  uint4 a0 = *reinterpret_cast<const uint4*>(&A[(size_t)(row0 + rA0) * K + pA0 * 8]);
  uint4 a1 = *reinterpret_cast<const uint4*>(&A[(size_t)(row0 + rA1) * K + pA1 * 8]);
  uint4 w0 = *reinterpret_cast<const uint4*>(&W[(size_t)(col0 + rW) * K + pW * 8]);
  for (int k0 = 0;;) {
    *reinterpret_cast<uint4*>(&Ah[rA0 * 40 + pA0 * 8]) = a0;
    *reinterpret_cast<uint4*>(&Ah[rA1 * 40 + pA1 * 8]) = a1;
    *reinterpret_cast<uint4*>(&Wh[rW * 40 + pW * 8]) = w0;
    __syncthreads();
    int kn = k0 + 32;
    if (kn < K) {
      a0 = *reinterpret_cast<const uint4*>(&A[(size_t)(row0 + rA0) * K + kn + pA0 * 8]);
      a1 = *reinterpret_cast<const uint4*>(&A[(size_t)(row0 + rA1) * K + kn + pA1 * 8]);
      w0 = *reinterpret_cast<const uint4*>(&W[(size_t)(col0 + rW) * K + kn + pW * 8]);
    }
    half8 af[4], wf[2];
#pragma unroll
    for (int m = 0; m < 4; m++)
      af[m] = *reinterpret_cast<const half8*>(&Ah[(wr + m * 16 + fr) * 40 + kb]);
#pragma unroll
    for (int n = 0; n < 2; n++)
      wf[n] = *reinterpret_cast<const half8*>(&Wh[(wc + n * 16 + fr) * 40 + kb]);
#pragma unroll
    for (int m = 0; m < 4; m++)
#pragma unroll
      for (int n = 0; n < 2; n++)
        acc[m][n] = __builtin_amdgcn_mfma_f32_16x16x32_f16(af[m], wf[n], acc[m][n], 0, 0, 0);
    if (kn >= K) break;
    __syncthreads();
    k0 = kn;
  }
  const int rl4 = (lane >> 4) * 4, cl = lane & 15;
#pragma unroll
  for (int m = 0; m < 4; m++) {
#pragma unroll
    for (int i = 0; i < 4; i++) {
      int row = row0 + wr + m * 16 + rl4 + i;
      float cb = (MODE == 4 || MODE == 5) ? (float)cnt[row] : 1.f;
      int dg = (MODE == 4 || MODE == 5) ? deg[row] : 0;
      int brow = (MODE == 7) ? batch2[row] : 0;
#pragma unroll
      for (int n = 0; n < 2; n++) {
        int col = col0 + wc + n * 16 + cl;
        float v = acc[m][n][i];
        size_t oi = (size_t)row * 256 + col;
        if (MODE == 4 || MODE == 5) {
          v += cb * bias[col];
          float sc = expf(scale[dg * 256 + col]);
          if (MODE == 4) Cadd[oi] += sc * v;
          else Cadd[oi] = sc * v;
          if (Cf) Cf[oi] = (f16)v;
        } else if (MODE == 7) {
          v += bias[col];
          float nv = C[oi] + Cadd[oi] + expf(vs2[col]) * vout2[(size_t)brow * 256 + col]
                   + expf(scale[col]) * v;
          Cf[oi] = (f16)nv;
        } else if (MODE == 6) {
          v += bias[col];
          float s1 = v, s2 = v * v;
#pragma unroll
          for (int o_ = 1; o_ < 16; o_ <<= 1) {
            s1 += __shfl_xor(s1, o_);
            s2 += __shfl_xor(s2, o_);
          }
          float mean = s1 * (1.f / 16.f);
          float var = s2 * (1.f / 16.f) - mean * mean;
          float gnv = (v - mean) * rsqrtf(var + 1e-5f);
          if (C) C[oi] = gnv;
          if (Cf) Cf[oi] = (f16)gnv;
        } else {
          if (bias) v += bias[col];
          if (C) C[oi] = v;
          if (Cf) Cf[oi] = (f16)v;
        }
      }
    }
  }
}

// ---------------- conv node: per-node loop over CSR edges; bond+GN+glin+segment-sum fused ----------------
// thread = (node, group). dst row read once; accumulate glin outputs in f32; write f16 node sum.
__global__ __launch_bounds__(256) void conv_node_kernel(
    const f16* __restrict__ xp, const int* __restrict__ ea_s,
    const int* __restrict__ src_s, const int* __restrict__ off,
    const float* __restrict__ bond_emb, const float* __restrict__ gate_w,
    const float* __restrict__ val_w, f16* __restrict__ out) {
  constexpr int RS = 264;  // f16 row stride: 256 + 8 pad
  __shared__ f16 sg[16 * RS];
  __shared__ f16 sv[16 * RS];
  int tid = threadIdx.x;
  for (int i = tid; i < 4096; i += 256) {
    int g = i >> 8, rem = i & 255;
    sg[g * RS + rem] = (f16)gate_w[i];
    sv[g * RS + rem] = (f16)val_w[i];
  }
  __syncthreads();
  int idx = blockIdx.x * 256 + tid;
  int n = idx >> 4, g = idx & 15;
  int j0 = off[n], j1 = off[n + 1];
  // dst row chunk (constant across this node's edges)
  half8 xd0 = *reinterpret_cast<const half8*>(&xp[(size_t)n * 256 + g * 16]);
  half8 xd1 = *reinterpret_cast<const half8*>(&xp[(size_t)n * 256 + g * 16 + 8]);
  float xdf[16];
#pragma unroll
  for (int i = 0; i < 8; i++) { xdf[i] = (float)xd0[i]; xdf[i + 8] = (float)xd1[i]; }
  const f16* gRow = &sg[g * RS];
  const f16* vRow = &sv[g * RS];
  float accv[16] = {0.f, 0.f, 0.f, 0.f, 0.f, 0.f, 0.f, 0.f,
                    0.f, 0.f, 0.f, 0.f, 0.f, 0.f, 0.f, 0.f};
  for (int j = j0; j < j1; j++) {
    int a0 = ea_s[j * 3 + 0], a1 = ea_s[j * 3 + 1], a2 = ea_s[j * 3 + 2];
    int s = src_s[j];
    half8 xs0 = *reinterpret_cast<const half8*>(&xp[(size_t)s * 256 + g * 16]);
    half8 xs1 = *reinterpret_cast<const half8*>(&xp[(size_t)s * 256 + g * 16 + 8]);
    const float4* b0p = reinterpret_cast<const float4*>(&bond_emb[a0 * 256 + g * 16]);
    const float4* b1p = reinterpret_cast<const float4*>(&bond_emb[2048 + a1 * 256 + g * 16]);
    const float4* b2p = reinterpret_cast<const float4*>(&bond_emb[4096 + a2 * 256 + g * 16]);
    float xg[16], xv[16];
    float mg = 0.f, mv = 0.f;
#pragma unroll
    for (int q = 0; q < 4; q++) {
      float4 b0 = b0p[q], b1 = b1p[q], b2 = b2p[q];
#pragma unroll
      for (int t = 0; t < 4; t++) {
        int i = q * 4 + t;
        float bo = (&b0.x)[t] + (&b1.x)[t] + (&b2.x)[t];
        float xs = (i < 8) ? (float)xs0[i & 7] : (float)xs1[i & 7];
        xg[i] = xdf[i] + bo;
        xv[i] = xs + bo;
        mg += xg[i];
        mv += xv[i];
      }
    }
    mg *= (1.f / 16.f);
    mv *= (1.f / 16.f);
    float vg = 0.f, vv = 0.f;
#pragma unroll
    for (int i = 0; i < 16; i++) {
      float dg_ = xg[i] - mg, dv_ = xv[i] - mv;
      vg += dg_ * dg_;
      vv += dv_ * dv_;
    }
    float rg = rsqrtf(vg * (1.f / 16.f) + 1e-5f);
    float rv = rsqrtf(vv * (1.f / 16.f) + 1e-5f);
#ifdef HAVE_FDOT2
    half2v xgh[8], xvh[8];
#pragma unroll
    for (int q = 0; q < 8; q++) {
      xgh[q][0] = (f16)((xg[2 * q] - mg) * rg);
      xgh[q][1] = (f16)((xg[2 * q + 1] - mg) * rg);
      xvh[q][0] = (f16)((xv[2 * q] - mv) * rv);
      xvh[q][1] = (f16)((xv[2 * q + 1] - mv) * rv);
    }
#else
#pragma unroll
    for (int i = 0; i < 16; i++) {
      xg[i] = (xg[i] - mg) * rg;
      xv[i] = (xv[i] - mv) * rv;
    }
#endif
#pragma unroll
    for (int o = 0; o < 16; o++) {
      half8 gA = *reinterpret_cast<const half8*>(&gRow[o * 16]);
      half8 gB = *reinterpret_cast<const half8*>(&gRow[o * 16 + 8]);
      half8 vA = *reinterpret_cast<const half8*>(&vRow[o * 16]);
      half8 vB = *reinterpret_cast<const half8*>(&vRow[o * 16 + 8]);
      float ag = 0.f, av = 0.f;
#ifdef HAVE_FDOT2
#pragma unroll
      for (int q = 0; q < 4; q++) {
        half2v ga = {gA[2 * q], gA[2 * q + 1]};
        half2v gb = {gB[2 * q], gB[2 * q + 1]};
        half2v va = {vA[2 * q], vA[2 * q + 1]};
        half2v vb = {vB[2 * q], vB[2 * q + 1]};
        ag = __builtin_amdgcn_fdot2(xgh[q], ga, ag, false);
        ag = __builtin_amdgcn_fdot2(xgh[q + 4], gb, ag, false);
        av = __builtin_amdgcn_fdot2(xvh[q], va, av, false);
        av = __builtin_amdgcn_fdot2(xvh[q + 4], vb, av, false);
      }
#else
#pragma unroll
      for (int i = 0; i < 8; i++) {
        ag += xg[i] * (float)gA[i] + xg[i + 8] * (float)gB[i];
        av += xv[i] * (float)vA[i] + xv[i + 8] * (float)vB[i];
      }
#endif
      accv[o] += fmaxf(ag, 0.f) * av;
    }
  }
  f16 res[16];
#pragma unroll
  for (int o = 0; o < 16; o++) res[o] = (f16)accv[o];
  uint4* op = reinterpret_cast<uint4*>(&out[(size_t)n * 256 + g * 16]);
  op[0] = reinterpret_cast<const uint4*>(res)[0];
  op[1] = reinterpret_cast<const uint4*>(res)[1];
}

// ---------------- glb middle (f16 input, pre-normalized): glin + relu*mul ----------------
template <int DOUT>
__global__ __launch_bounds__(256) void glb_mid_h_kernel(
    const f16* __restrict__ X, const float* __restrict__ gate_w,
    const float* __restrict__ val_w, f16* __restrict__ out) {
  constexpr int RS = DOUT * 16 + 8;
  __shared__ f16 sg[16 * RS];
  __shared__ f16 sv[16 * RS];
  int tid = threadIdx.x;
  for (int i = tid; i < 16 * DOUT * 16; i += 256) {
    int g = i / (DOUT * 16), rem = i % (DOUT * 16);
    sg[g * RS + rem] = (f16)gate_w[i];
    sv[g * RS + rem] = (f16)val_w[i];
  }
  __syncthreads();
  int idx = blockIdx.x * 256 + tid;
  int n = idx >> 4, g = idx & 15;
  half8 x0 = *reinterpret_cast<const half8*>(&X[(size_t)n * 256 + g * 16]);
  half8 x1 = *reinterpret_cast<const half8*>(&X[(size_t)n * 256 + g * 16 + 8]);
#ifdef HAVE_FDOT2
  half2v xh[8];
#pragma unroll
  for (int q = 0; q < 4; q++) {
    xh[q][0] = x0[2 * q]; xh[q][1] = x0[2 * q + 1];
    xh[q + 4][0] = x1[2 * q]; xh[q + 4][1] = x1[2 * q + 1];
  }
#else
  float x[16];
#pragma unroll
  for (int i = 0; i < 8; i++) { x[i] = (float)x0[i]; x[i + 8] = (float)x1[i]; }
#endif
  const f16* gRow = &sg[g * RS];
  const f16* vRow = &sv[g * RS];
  f16 res[DOUT];
#pragma unroll
  for (int o = 0; o < DOUT; o++) {
    half8 gA = *reinterpret_cast<const half8*>(&gRow[o * 16]);
    half8 gB = *reinterpret_cast<const half8*>(&gRow[o * 16 + 8]);
    half8 vA = *reinterpret_cast<const half8*>(&vRow[o * 16]);
    half8 vB = *reinterpret_cast<const half8*>(&vRow[o * 16 + 8]);
    float ag = 0.f, av = 0.f;
#ifdef HAVE_FDOT2
#pragma unroll
    for (int q = 0; q < 4; q++) {
      half2v gq = {gA[2 * q], gA[2 * q + 1]};
      half2v g2 = {gB[2 * q], gB[2 * q + 1]};
      half2v vq = {vA[2 * q], vA[2 * q + 1]};
      half2v v2 = {vB[2 * q], vB[2 * q + 1]};
      ag = __builtin_amdgcn_fdot2(xh[q], gq, ag, false);
      ag = __builtin_amdgcn_fdot2(xh[q + 4], g2, ag, false);
      av = __builtin_amdgcn_fdot2(xh[q], vq, av, false);
      av = __builtin_amdgcn_fdot2(xh[q + 4], v2, av, false);
    }
#else
#pragma unroll
    for (int i = 0; i < 8; i++) {
      ag += x[i] * (float)gA[i] + x[i + 8] * (float)gB[i];
      av += x[i] * (float)vA[i] + x[i + 8] * (float)vB[i];
    }
#endif
    res[o] = (f16)(fmaxf(ag, 0.f) * av);
  }
  f16* op = &out[(size_t)n * (16 * DOUT) + g * DOUT];
#pragma unroll
  for (int q = 0; q < DOUT / 8; q++)
    *reinterpret_cast<half8*>(&op[q * 8]) = *reinterpret_cast<const half8*>(&res[q * 8]);
}

// ---------------- fused VirtMessage ----------------
__global__ __launch_bounds__(256) void virt_fused_kernel(
    const float* __restrict__ h_in, const int* __restrict__ goff,
    const float* __restrict__ preW, const float* __restrict__ preb,
    const float* __restrict__ gateW, const float* __restrict__ valW,
    const float* __restrict__ postW, const float* __restrict__ postb,
    float* __restrict__ h_virt, float* __restrict__ vout) {
  __shared__ float sred[4][256];
  __shared__ float sx[256];
  __shared__ float xx[256];
  __shared__ float vv[512];
  int tid = threadIdx.x, b = blockIdx.x;
  int n0 = goff[b], n1 = goff[b + 1];
  int sub = tid >> 6, cg = tid & 63;
  float a0 = 0.f, a1 = 0.f, a2 = 0.f, a3 = 0.f;
  for (int n = n0 + sub; n < n1; n += 4) {
    float4 x = *reinterpret_cast<const float4*>(&h_in[(size_t)n * 256 + cg * 4]);
    a0 += x.x; a1 += x.y; a2 += x.z; a3 += x.w;
  }
  sred[sub][cg * 4 + 0] = a0;
  sred[sub][cg * 4 + 1] = a1;
  sred[sub][cg * 4 + 2] = a2;
  sred[sub][cg * 4 + 3] = a3;
  __syncthreads();
  float acc = h_virt[(size_t)b * 256 + tid] + sred[0][tid] + sred[1][tid] + sred[2][tid] + sred[3][tid];
  h_virt[(size_t)b * 256 + tid] = acc;
  sx[tid] = acc;
  __syncthreads();
  float dot = preb[tid];
  const float4* wrow = reinterpret_cast<const float4*>(&preW[(size_t)tid * 256]);
  const float4* sx4 = reinterpret_cast<const float4*>(sx);
#pragma unroll 8
  for (int q = 0; q < 64; q++) {
    float4 w = wrow[q];
    float4 s = sx4[q];
    dot += w.x * s.x + w.y * s.y + w.z * s.z + w.w * s.w;
  }
  float s1 = dot, s2 = dot * dot;
#pragma unroll
  for (int o_ = 1; o_ < 16; o_ <<= 1) {
    s1 += __shfl_xor(s1, o_);
    s2 += __shfl_xor(s2, o_);
  }
  float mean = s1 * (1.f / 16.f);
  float var = s2 * (1.f / 16.f) - mean * mean;
  xx[tid] = (dot - mean) * rsqrtf(var + 1e-5f);
  __syncthreads();
#pragma unroll
  for (int rep = 0; rep < 2; rep++) {
    int o = tid + rep * 256;
    int g = o >> 5, o2 = o & 31;
    const float4* gw = reinterpret_cast<const float4*>(&gateW[(size_t)(g * 32 + o2) * 16]);
    const float4* vw = reinterpret_cast<const float4*>(&valW[(size_t)(g * 32 + o2) * 16]);
    const float4* xg4 = reinterpret_cast<const float4*>(&xx[g * 16]);
    float ag = 0.f, av = 0.f;
#pragma unroll
    for (int q = 0; q < 4; q++) {
      float4 wg = gw[q], wv = vw[q], xq = xg4[q];
      ag += wg.x * xq.x + wg.y * xq.y + wg.z * xq.z + wg.w * xq.w;
      av += wv.x * xq.x + wv.y * xq.y + wv.z * xq.z + wv.w * xq.w;
    }
    vv[o] = fmaxf(ag, 0.f) * av;
  }
  __syncthreads();
  float outv = postb[tid];
  const float4* prow = reinterpret_cast<const float4*>(&postW[(size_t)tid * 512]);
  const float4* vv4 = reinterpret_cast<const float4*>(vv);
#pragma unroll 8
  for (int q = 0; q < 128; q++) {
    float4 w = prow[q], s = vv4[q];
    outv += w.x * s.x + w.y * s.y + w.z * s.z + w.w * s.w;
  }
  vout[(size_t)b * 256 + tid] = outv;
}

// ---------------- attention ----------------
// h_att layout: [b][h][head][v] = b*8192 + h*512 + head*16 + v
template <bool FIRST>
__global__ __launch_bounds__(256) void att_graph_kernel(
    const float* __restrict__ xv0, const float* __restrict__ k_w,
    const float* __restrict__ v_w, const int* __restrict__ goff,
    float* __restrict__ h_att, float* __restrict__ xk_sum) {
  __shared__ float kx[8][256];
  __shared__ float vx[8][256];
  __shared__ float rows[8][256];
  const int tid = threadIdx.x;
  const int b = blockIdx.x >> 1, half = blockIdx.x & 1;
  const int p = half * 256 + tid;
  const int g = p >> 5;
  const int headLocal = tid >> 4;
  const int head = p >> 4, h = p & 15;
  float wk[16], wv[16];
#pragma unroll
  for (int i = 0; i < 4; i++) {
    float4 k0 = *reinterpret_cast<const float4*>(&k_w[p * 16 + i * 4]);
    float4 v0 = *reinterpret_cast<const float4*>(&v_w[p * 16 + i * 4]);
    wk[i * 4 + 0] = k0.x; wk[i * 4 + 1] = k0.y; wk[i * 4 + 2] = k0.z; wk[i * 4 + 3] = k0.w;
    wv[i * 4 + 0] = v0.x; wv[i * 4 + 1] = v0.y; wv[i * 4 + 2] = v0.z; wv[i * 4 + 3] = v0.w;
  }
  float hacc[16];
  if (FIRST) {
#pragma unroll
    for (int j = 0; j < 16; j++) hacc[j] = 0.f;
  } else {
    const float* hg = &h_att[(size_t)b * 8192];
#pragma unroll
    for (int j = 0; j < 16; j++) hacc[j] = hg[h * 512 + head * 16 + j];
  }
  float ks = 0.f;
  const int n0 = goff[b], n1 = goff[b + 1];
  float r[8];
#pragma unroll
  for (int nn = 0; nn < 8; nn++) {
    int n = n0 + nn;
    r[nn] = (n < n1) ? xv0[(size_t)n * 256 + tid] : 0.f;
  }
  for (int nbase = n0; nbase < n1; nbase += 8) {
#pragma unroll
    for (int nn = 0; nn < 8; nn++) rows[nn][tid] = r[nn];
    __syncthreads();
#pragma unroll
    for (int nn = 0; nn < 8; nn++) {
      int n = nbase + 8 + nn;
      r[nn] = (n < n1) ? xv0[(size_t)n * 256 + tid] : 0.f;
    }
#pragma unroll
    for (int nn = 0; nn < 8; nn++) {
      const float4* rp = reinterpret_cast<const float4*>(&rows[nn][g * 16]);
      float aK = 0.f, aV = 0.f;
#pragma unroll
      for (int q = 0; q < 4; q++) {
        float4 x0 = rp[q];
#pragma unroll
        for (int t = 0; t < 4; t++) {
          float e0 = (&x0.x)[t];
          aK += e0 * wk[q * 4 + t];
          aV += e0 * wv[q * 4 + t];
        }
      }
      bool valid = (nbase + nn) < n1;
      float ek = valid ? expf(aK * 0.25f) : 0.f;
      kx[nn][tid] = ek;
      vx[nn][tid] = aV;
      ks += ek;
    }
    __syncthreads();
#pragma unroll
    for (int nn = 0; nn < 8; nn++) {
      float kk = kx[nn][tid];
      const float4* vp = reinterpret_cast<const float4*>(&vx[nn][headLocal * 16]);
#pragma unroll
      for (int q = 0; q < 4; q++) {
        float4 vq = vp[q];
        hacc[q * 4 + 0] += kk * vq.x;
        hacc[q * 4 + 1] += kk * vq.y;
        hacc[q * 4 + 2] += kk * vq.z;
        hacc[q * 4 + 3] += kk * vq.w;
      }
    }
    __syncthreads();
  }
  float* hgo = &h_att[(size_t)b * 8192];
#pragma unroll
  for (int j = 0; j < 16; j++) hgo[h * 512 + head * 16 + j] = hacc[j];
  xk_sum[(size_t)b * 512 + p] = ks;
}

// Per-graph att_out
__global__ __launch_bounds__(256) void att_out_kernel(
    const float* __restrict__ xv0, const float* __restrict__ q_w,
    const float* __restrict__ xk_sum, const float* __restrict__ h_att,
    const int* __restrict__ goff, f16* __restrict__ out) {
  __shared__ float sqw[16 * 260];
  __shared__ float hat[16 * 644];
  int tid = threadIdx.x, b = blockIdx.x;
  for (int i = tid; i < 8192; i += 256) {
    int g = i >> 9, rem = i & 511;
    sqw[g * 260 + rem] = q_w[i];
  }
  for (int i = tid; i < 8192; i += 256) {
    int h = i >> 9, rem = i & 511;
    int head = rem >> 4, v = rem & 15;
    hat[h * 644 + head * 20 + v] = h_att[(size_t)b * 8192 + i];
  }
  __syncthreads();
  int n0 = goff[b], n1 = goff[b + 1];
  int nl = tid >> 5, head = tid & 31;
  int g = head >> 1, j = head & 1;
  const float* ks = &xk_sum[(size_t)b * 512 + head * 16];
  for (int nbase = n0; nbase < n1; nbase += 8) {
    int n = nbase + nl;
    if (n >= n1) continue;
    float x[16];
    const float4* xp4 = reinterpret_cast<const float4*>(&xv0[(size_t)n * 256 + g * 16]);
#pragma unroll
    for (int q = 0; q < 4; q++) {
      float4 xq = xp4[q];
#pragma unroll
      for (int t = 0; t < 4; t++) x[q * 4 + t] = (&xq.x)[t];
    }
    float qv[16];
    float denom = 0.f;
#pragma unroll
    for (int h = 0; h < 16; h++) {
      const float4* wp = reinterpret_cast<const float4*>(&sqw[g * 260 + (j * 16 + h) * 16]);
      float a = 0.f;
#pragma unroll
      for (int q = 0; q < 4; q++) {
        float4 wq = wp[q];
#pragma unroll
        for (int t = 0; t < 4; t++) a += x[q * 4 + t] * (&wq.x)[t];
      }
      float e = expf(a * 0.25f);
      qv[h] = e;
      denom += e * ks[h];
    }
    float inv = 1.f / denom;
    float acc[16] = {0.f, 0.f, 0.f, 0.f, 0.f, 0.f, 0.f, 0.f,
                     0.f, 0.f, 0.f, 0.f, 0.f, 0.f, 0.f, 0.f};
#pragma unroll
    for (int h = 0; h < 16; h++) {
      float qh = qv[h];
      const float4* hp = reinterpret_cast<const float4*>(&hat[h * 644 + head * 20]);
#pragma unroll
      for (int q = 0; q < 4; q++) {
        float4 vq = hp[q];
        acc[q * 4 + 0] += qh * vq.x;
        acc[q * 4 + 1] += qh * vq.y;
        acc[q * 4 + 2] += qh * vq.z;
        acc[q * 4 + 3] += qh * vq.w;
      }
    }
    f16 res[16];
#pragma unroll
    for (int v = 0; v < 16; v++) res[v] = (f16)(acc[v] * inv);
    uint4* op = reinterpret_cast<uint4*>(&out[(size_t)n * 512 + head * 16]);
    op[0] = reinterpret_cast<const uint4*>(res)[0];
    op[1] = reinterpret_cast<const uint4*>(res)[1];
  }
}

// ---------------- host driver ----------------

extern "C" void kernel_launch(void* const* d_in, const int* in_sizes, int n_in,
                              void* d_out, int out_size, void* d_ws, size_t ws_size,
                              hipStream_t stream) {
  const int* x_feat = (const int*)d_in[0];
  const int* eidx = (const int*)d_in[1];
  const int* eattr = (const int*)d_in[2];
  const int* batch = (const int*)d_in[3];
  const float* edist = (const float*)d_in[5];
  const float* atom_emb = (const float*)d_in[6];
  const float* bond2d = (const float*)d_in[7];
  const float* gmeans = (const float*)d_in[8];
  const float* gstds = (const float*)d_in[9];
  const float* attn_w = (const float*)d_in[10];
  const float* attn_b = (const float*)d_in[11];
  const float* scale_both = (const float*)d_in[12];
  const float* conv_bond_emb = (const float*)d_in[13];
  const float* conv_pre_w = (const float*)d_in[14];
  const float* conv_gate_w = (const float*)d_in[15];
  const float* conv_val_w = (const float*)d_in[16];
  const float* conv_post_w = (const float*)d_in[17];
  const float* conv_post_b = (const float*)d_in[18];
  const float* conv_scale = (const float*)d_in[19];
  const float* virt_pre_w = (const float*)d_in[20];
  const float* virt_pre_b = (const float*)d_in[21];
  const float* virt_gate_w = (const float*)d_in[22];
  const float* virt_val_w = (const float*)d_in[23];
  const float* virt_post_w = (const float*)d_in[24];
  const float* virt_post_b = (const float*)d_in[25];
  const float* virt_scale = (const float*)d_in[26];
  const float* att_pre_w = (const float*)d_in[27];
  const float* att_pre_b = (const float*)d_in[28];
  const float* att_q_w = (const float*)d_in[29];
  const float* att_k_w = (const float*)d_in[30];
  const float* att_v_w = (const float*)d_in[31];
  const float* att_post_w = (const float*)d_in[32];
  const float* att_post_b = (const float*)d_in[33];
  const float* att_scale = (const float*)d_in[34];
  const float* main_pre_w = (const float*)d_in[35];
  const float* main_pre_b = (const float*)d_in[36];
  const float* main_gate_w = (const float*)d_in[37];
  const float* main_val_w = (const float*)d_in[38];
  const float* main_post_w = (const float*)d_in[39];
  const float* main_post_b = (const float*)d_in[40];

  const int* src = eidx;
  const int* dst = eidx + EE;

  float* ws = (float*)d_ws;
  float* h_in = ws;
  float* x_out = ws + ND;
  float* nodeA = ws + 2 * ND;
  f16* h_inH = (f16*)(ws + 3 * ND);
  f16* xrawH = (f16*)(ws + 3 * ND + ND / 2);
  f16* hTmp = (f16*)(ws + 4 * ND);
  f16* gnH = (f16*)(ws + 4 * ND + ND / 2);
  f16* msgH = (f16*)(ws + 5 * ND);            // 3*ND halfs (edge msgs / att_out / main mid)
  float* sm = ws + 7 * ND;
  f16* hW = (f16*)sm;                          // weights fp16 pool
  float* h_virt = sm + 1179648;
  float* h_att = h_virt + 65536;
  float* xk_sum = h_att + 2097152;
  float* vout = xk_sum + 131072;               // B*256
  int* cnt = (int*)(vout + 65536);
  int* deg = cnt + NN;
  int* goff = deg + NN;
  int* off = goff + BB + 1;
  int* cursor = off + NN + 1;
  int* elist = cursor + NN;
  int* ea_s = elist + EE;
  int* src_s = ea_s + 3 * EE;
  float* ed_s = (float*)(src_s + EE);

  f16* wCpre = hW;
  f16* wCpost = hW + 524288;
  f16* wApre = hW + 1048576;
  f16* wApost = hW + 1179648;
  f16* wMpre = hW + 1441792;
  f16* wMpost = hW + 1572864;

  auto cvt = [&](const float* in, f16* out, int n) {
    f2h_kernel<<<n / 4 / 256, 256, 0, stream>>>(in, out, n / 4);
  };

  cvt(conv_pre_w, wCpre, 524288);
  cvt(conv_post_w, wCpost, 524288);
  cvt(att_pre_w, wApre, 131072);
  cvt(att_post_w, wApost, 262144);
  cvt(main_pre_w, wMpre, 131072);
  cvt(main_post_w, wMpost, 393216);

  // degree + graph offsets + CSR + gathered edge data
  (void)hipMemsetAsync(cnt, 0, NN * sizeof(int), stream);
  count_deg_kernel<<<EE / 256, 256, 0, stream>>>(dst, cnt, EE);
  clip_deg_kernel<<<NN / 256, 256, 0, stream>>>(cnt, deg, NN);
  goff_kernel<<<(NN + 256) / 256, 256, 0, stream>>>(batch, goff, NN, BB);
  scan_off_kernel<<<1, 256, 0, stream>>>(cnt, off);
  copy_i_kernel<<<NN / 256, 256, 0, stream>>>(off, cursor, NN);
  fill_elist_kernel<<<EE / 256, 256, 0, stream>>>(dst, cursor, elist, EE);
  gather_edges_kernel<<<EE / 256, 256, 0, stream>>>(elist, eattr, src, dst, edist,
                                                    ea_s, src_s, ed_s);

  // initial node features
  edge_feat_kernel<<<EE / 4, 256, 0, stream>>>(ea_s, ed_s, bond2d, gmeans, gstds,
                                               attn_w, attn_b, msgH);
  seg_reduce_f_kernel<<<NN / 4, 256, 0, stream>>>(msgH, off, x_out);
  atom_finish_kernel<<<NN * 64 / 256, 256, 0, stream>>>(x_feat, atom_emb, scale_both, deg,
                                                        x_out, h_in, h_inH);
  (void)hipMemsetAsync(h_virt, 0, 65536 * 4, stream);

  const dim3 gN(NN / 128, 4);
  const int n4 = (int)(ND / 4);

  for (int l = 0; l < 2; l++) {
    // ---- ConvMessage ----
    const f16* curH = h_inH;
    for (int k = 0; k < 4; k++) {
      if (k == 2) {
        add3h_kernel<<<n4 / 256, 256, 0, stream>>>(xrawH, h_in, x_out, n4);
        curH = xrawH;
      }
      size_t lk = (size_t)(l * 4 + k);
      hgemm_kernel<0><<<gN, 256, 0, stream>>>(curH, wCpre + lk * 65536, nullptr, nullptr,
                                              nullptr, nullptr, nullptr, nullptr, hTmp,
                                              nullptr, nullptr, nullptr, 256);
      conv_node_kernel<<<NN * 16 / 256, 256, 0, stream>>>(
          hTmp, ea_s, src_s, off, conv_bond_emb + lk * 6144,
          conv_gate_w + lk * 4096, conv_val_w + lk * 4096, gnH);
      if (k == 0 || k == 2)
        hgemm_kernel<5><<<gN, 256, 0, stream>>>(gnH, wCpost + lk * 65536,
                                                conv_post_b + lk * 256, conv_scale + lk * 1024,
                                                cnt, deg, nullptr, x_out, xrawH,
                                                nullptr, nullptr, nullptr, 256);
      else
        hgemm_kernel<4><<<gN, 256, 0, stream>>>(gnH, wCpost + lk * 65536,
                                                conv_post_b + lk * 256, conv_scale + lk * 1024,
                                                cnt, deg, nullptr, x_out, xrawH,
                                                nullptr, nullptr, nullptr, 256);
      curH = xrawH;
    }
    // h_out = h_in + x_out folded into MODE 7 epilogue below.

    // ---- VirtMessage (fused) ----
    virt_fused_kernel<<<BB, 256, 0, stream>>>(
        h_in, goff, virt_pre_w + (size_t)l * 65536, virt_pre_b + (size_t)l * 256,
        virt_gate_w + (size_t)l * 8192, virt_val_w + (size_t)l * 8192,
        virt_post_w + (size_t)l * 131072, virt_post_b + (size_t)l * 256, h_virt, vout);

    // ---- AttMessage ----
    hgemm_kernel<6><<<gN, 256, 0, stream>>>(h_inH, wApre + (size_t)l * 65536,
                                            att_pre_b + (size_t)l * 256, nullptr, nullptr,
                                            nullptr, nodeA, nullptr, nullptr,
                                            nullptr, nullptr, nullptr, 256);
    if (l == 0)
      att_graph_kernel<true><<<BB * 2, 256, 0, stream>>>(
          nodeA, att_k_w + (size_t)l * 8192, att_v_w + (size_t)l * 8192, goff, h_att, xk_sum);
    else
      att_graph_kernel<false><<<BB * 2, 256, 0, stream>>>(
          nodeA, att_k_w + (size_t)l * 8192, att_v_w + (size_t)l * 8192, goff, h_att, xk_sum);
    att_out_kernel<<<BB, 256, 0, stream>>>(
        nodeA, att_q_w + (size_t)l * 8192, xk_sum, h_att, goff, msgH);
    // hTmp = f16(h_in + x_out + exp(vs)*vout[batch] + exp(as)*attpost)
    hgemm_kernel<7><<<gN, 256, 0, stream>>>(msgH, wApost + (size_t)l * 131072,
                                            att_post_b + (size_t)l * 256,
                                            att_scale + (size_t)l * 256, nullptr, nullptr,
                                            h_in, x_out, hTmp,
                                            virt_scale + (size_t)l * 256, vout, batch, 512);

    // ---- main gated block ----
    hgemm_kernel<6><<<gN, 256, 0, stream>>>(hTmp, wMpre + (size_t)l * 65536,
                                            main_pre_b + (size_t)l * 256, nullptr, nullptr,
                                            nullptr, nullptr, nullptr, gnH,
                                            nullptr, nullptr, nullptr, 256);
    glb_mid_h_kernel<48><<<NN * 16 / 256, 256, 0, stream>>>(
        gnH, main_gate_w + (size_t)l * 12288, main_val_w + (size_t)l * 12288, msgH);
    float* hdst = (l == 1) ? (float*)d_out : h_in;
    f16* hdstH = (l == 1) ? nullptr : h_inH;
    hgemm_kernel<0><<<gN, 256, 0, stream>>>(msgH, wMpost + (size_t)l * 196608,
                                            main_post_b + (size_t)l * 256, nullptr, nullptr,
                                            nullptr, hdst, nullptr, hdstH,
                                            nullptr, nullptr, nullptr, 768);
  }
}

// Round 16
// 973.860 us; speedup vs baseline: 1.4331x; 1.4331x over previous
//
#include <hip/hip_runtime.h>
#include <cstdint>
#include <cstddef>
#include <type_traits>

#define NN 16384
#define EE 49152
#define BB 256
// D=256, G=16, 16 channels per group, HD=16

typedef _Float16 f16;
typedef _Float16 half8 __attribute__((ext_vector_type(8)));
typedef _Float16 half4v __attribute__((ext_vector_type(4)));
typedef _Float16 half2v __attribute__((ext_vector_type(2)));
typedef float floatx4 __attribute__((ext_vector_type(4)));

#if defined(__has_builtin)
#if __has_builtin(__builtin_amdgcn_fdot2)
#define HAVE_FDOT2 1
#endif
#endif

static constexpr size_t ND = (size_t)NN * 256;

// ---------------- setup kernels ----------------

__global__ __launch_bounds__(256) void count_deg_kernel(const int* __restrict__ dst, int* __restrict__ cnt, int e) {
  int i = blockIdx.x * 256 + threadIdx.x;
  if (i < e) atomicAdd(&cnt[dst[i]], 1);
}
__global__ __launch_bounds__(256) void clip_deg_kernel(const int* __restrict__ cnt, int* __restrict__ deg, int n) {
  int i = blockIdx.x * 256 + threadIdx.x;
  if (i < n) { int v = cnt[i] - 1; deg[i] = v < 0 ? 0 : (v > 3 ? 3 : v); }
}
__global__ __launch_bounds__(256) void goff_kernel(const int* __restrict__ batch, int* __restrict__ goff, int n, int b) {
  int i = blockIdx.x * 256 + threadIdx.x;
  if (i > n) return;
  int cur = (i < n) ? batch[i] : b;
  int prev = (i == 0) ? -1 : batch[i - 1];
  for (int x = prev + 1; x <= cur; x++) goff[x] = i;
}
__global__ __launch_bounds__(256) void scan_off_kernel(const int* __restrict__ cnt, int* __restrict__ off) {
  __shared__ int part[256];
  int tid = threadIdx.x;
  int base = tid * 64;
  int s = 0;
  for (int i = 0; i < 64; i++) s += cnt[base + i];
  part[tid] = s;
  __syncthreads();
  for (int o = 1; o < 256; o <<= 1) {
    int t = (tid >= o) ? part[tid - o] : 0;
    __syncthreads();
    part[tid] += t;
    __syncthreads();
  }
  int run = (tid == 0) ? 0 : part[tid - 1];
  for (int i = 0; i < 64; i++) {
    off[base + i] = run;
    run += cnt[base + i];
  }
  if (tid == 255) off[NN] = run;
}
__global__ __launch_bounds__(256) void copy_i_kernel(const int* __restrict__ a, int* __restrict__ b, int n) {
  int i = blockIdx.x * 256 + threadIdx.x;
  if (i < n) b[i] = a[i];
}
__global__ __launch_bounds__(256) void fill_elist_kernel(const int* __restrict__ dst,
    int* __restrict__ cursor, int* __restrict__ elist, int e) {
  int i = blockIdx.x * 256 + threadIdx.x;
  if (i < e) {
    int p = atomicAdd(&cursor[dst[i]], 1);
    elist[p] = i;
  }
}
// gather edge data into CSR (dst-sorted) order
__global__ __launch_bounds__(256) void gather_edges_kernel(const int* __restrict__ elist,
    const int* __restrict__ eattr, const int* __restrict__ src, const int* __restrict__ dst,
    const float* __restrict__ edist, int* __restrict__ ea_s, int* __restrict__ src_s,
    int* __restrict__ dst_s, float* __restrict__ ed_s) {
  int j = blockIdx.x * 256 + threadIdx.x;
  if (j >= EE) return;
  int e = elist[j];
  ea_s[j * 3 + 0] = eattr[e * 3 + 0];
  ea_s[j * 3 + 1] = eattr[e * 3 + 1];
  ea_s[j * 3 + 2] = eattr[e * 3 + 2];
  src_s[j] = src[e];
  dst_s[j] = dst[e];
  ed_s[j] = edist[e];
}
// dstH = f16(a + b)
__global__ __launch_bounds__(256) void add3h_kernel(f16* __restrict__ dstH,
    const float* __restrict__ a, const float* __restrict__ b, int n4) {
  int i = blockIdx.x * 256 + threadIdx.x;
  if (i >= n4) return;
  float4 x = reinterpret_cast<const float4*>(a)[i];
  float4 y = reinterpret_cast<const float4*>(b)[i];
  half4v h;
  h[0] = (f16)(x.x + y.x); h[1] = (f16)(x.y + y.y);
  h[2] = (f16)(x.z + y.z); h[3] = (f16)(x.w + y.w);
  reinterpret_cast<half4v*>(dstH)[i] = h;
}
__global__ __launch_bounds__(256) void f2h_kernel(const float* __restrict__ in, f16* __restrict__ out, int n4) {
  int i = blockIdx.x * 256 + threadIdx.x;
  if (i >= n4) return;
  float4 v = reinterpret_cast<const float4*>(in)[i];
  half4v o;
  o[0] = (f16)v.x; o[1] = (f16)v.y; o[2] = (f16)v.z; o[3] = (f16)v.w;
  reinterpret_cast<half4v*>(out)[i] = o;
}

// ---------------- segment reduce over CONTIGUOUS CSR rows ----------------
template <typename OUT>
__global__ __launch_bounds__(256) void seg_reduce_kernel(const f16* __restrict__ msg,
    const int* __restrict__ off, OUT* __restrict__ out) {
  int idx = blockIdx.x * 256 + threadIdx.x;
  int n = idx >> 6, c0 = (idx & 63) * 4;
  int j0 = off[n], j1 = off[n + 1];
  float a0 = 0.f, a1 = 0.f, a2 = 0.f, a3 = 0.f;
  int j = j0;
  for (; j + 1 < j1; j += 2) {
    half4v m0 = *reinterpret_cast<const half4v*>(&msg[(size_t)j * 256 + c0]);
    half4v m1 = *reinterpret_cast<const half4v*>(&msg[(size_t)(j + 1) * 256 + c0]);
    a0 += (float)m0[0] + (float)m1[0];
    a1 += (float)m0[1] + (float)m1[1];
    a2 += (float)m0[2] + (float)m1[2];
    a3 += (float)m0[3] + (float)m1[3];
  }
  if (j < j1) {
    half4v m0 = *reinterpret_cast<const half4v*>(&msg[(size_t)j * 256 + c0]);
    a0 += (float)m0[0]; a1 += (float)m0[1]; a2 += (float)m0[2]; a3 += (float)m0[3];
  }
  if constexpr (std::is_same<OUT, float>::value) {
    float4 o = {a0, a1, a2, a3};
    *reinterpret_cast<float4*>(&out[(size_t)n * 256 + c0]) = o;
  } else {
    half4v o;
    o[0] = (f16)a0; o[1] = (f16)a1; o[2] = (f16)a2; o[3] = (f16)a3;
    *reinterpret_cast<half4v*>(&out[(size_t)n * 256 + c0]) = o;
  }
}

// ---------------- initial edge / node features (CSR order) ----------------

__global__ __launch_bounds__(256) void edge_feat_kernel(
    const int* __restrict__ ea_s, const float* __restrict__ ed_s,
    const float* __restrict__ bond2d, const float* __restrict__ gmeans,
    const float* __restrict__ gstds, const float* __restrict__ attn_w,
    const float* __restrict__ attn_b, f16* __restrict__ msg) {
  int lane = threadIdx.x & 63;
  int j = blockIdx.x * 4 + (threadIdx.x >> 6);
  if (j >= EE) return;
  int a0 = ea_s[j * 3 + 0], a1 = ea_s[j * 3 + 1], a2 = ea_s[j * 3 + 2];
  float dist = ed_s[j];
  const float SQ2PI = sqrtf(2.0f * 3.14159f);
  int c0 = lane * 4;
  float4 b0 = *reinterpret_cast<const float4*>(&bond2d[a0 * 256 + c0]);
  float4 b1 = *reinterpret_cast<const float4*>(&bond2d[2048 + a1 * 256 + c0]);
  float4 b2 = *reinterpret_cast<const float4*>(&bond2d[4096 + a2 * 256 + c0]);
  float4 gm = *reinterpret_cast<const float4*>(&gmeans[c0]);
  float4 gs = *reinterpret_cast<const float4*>(&gstds[c0]);
  float4 w2 = *reinterpret_cast<const float4*>(&attn_w[c0]);
  float4 w3 = *reinterpret_cast<const float4*>(&attn_w[256 + c0]);
  float h2[4], h3[4];
  float part = 0.f;
#pragma unroll
  for (int i = 0; i < 4; i++) {
    h2[i] = (&b0.x)[i] + (&b1.x)[i] + (&b2.x)[i];
    float sd = fabsf((&gs.x)[i]) + 0.01f;
    float df = (dist - (&gm.x)[i]) / sd;
    h3[i] = expf(-0.5f * df * df) / (SQ2PI * sd);
    part += (&w2.x)[i] * h2[i] + (&w3.x)[i] * h3[i];
  }
#pragma unroll
  for (int off = 32; off > 0; off >>= 1) part += __shfl_xor(part, off);
  float wg = 1.f / (1.f + expf(-(part + attn_b[0])));
  half4v o;
#pragma unroll
  for (int i = 0; i < 4; i++) o[i] = (f16)(wg * h2[i] + (1.f - wg) * h3[i]);
  *reinterpret_cast<half4v*>(&msg[(size_t)j * 256 + c0]) = o;
}

__global__ __launch_bounds__(256) void atom_finish_kernel(
    const int* __restrict__ xf, const float* __restrict__ emb,
    const float* __restrict__ scale_both, const int* __restrict__ deg,
    const float* __restrict__ tmp, float* __restrict__ h_in, f16* __restrict__ h_inH) {
  int idx = blockIdx.x * 256 + threadIdx.x;
  int n = idx >> 6, c = (idx & 63) * 4;
  float a0 = 0.f, a1 = 0.f, a2 = 0.f, a3 = 0.f;
#pragma unroll
  for (int f = 0; f < 9; f++) {
    int v = xf[n * 9 + f];
    float4 e = *reinterpret_cast<const float4*>(&emb[((size_t)(f * 128 + v)) * 256 + c]);
    a0 += e.x; a1 += e.y; a2 += e.z; a3 += e.w;
  }
  int dg = deg[n];
  float4 s = *reinterpret_cast<const float4*>(&scale_both[dg * 256 + c]);
  float4 t = *reinterpret_cast<const float4*>(&tmp[(size_t)n * 256 + c]);
  float4 r;
  r.x = a0 + expf(s.x) * t.x; r.y = a1 + expf(s.y) * t.y;
  r.z = a2 + expf(s.z) * t.z; r.w = a3 + expf(s.w) * t.w;
  *reinterpret_cast<float4*>(&h_in[(size_t)n * 256 + c]) = r;
  half4v h;
  h[0] = (f16)r.x; h[1] = (f16)r.y; h[2] = (f16)r.z; h[3] = (f16)r.w;
  *reinterpret_cast<half4v*>(&h_inH[(size_t)n * 256 + c]) = h;
}

// ---------------- fp16 MFMA GEMM, tile 128x64, 4 waves (2x2), BK=32, reg prefetch ----------------
// MODE 0: v=acc(+bias); C?=v; Cf?=f16(v)
// MODE 4: v=acc+cnt[row]*bias[col]; Cadd[oi]+=expf(scale[deg[row]*256+col])*v; Cf?=f16(v)
// MODE 5: like 4 but Cadd[oi]= (init store)
// MODE 6: v=acc+bias; GroupNorm per 16-col group (16-lane shuffles); C?=gn; Cf?=f16(gn)
// MODE 7: v=acc+bias; nv=C[oi]+Cadd[oi] + expf(vs2[col])*vout2[batch2[row]*256+col] + expf(scale[col])*v; Cf=f16(nv)
template <int MODE>
__global__ __launch_bounds__(256) void hgemm_kernel(
    const f16* __restrict__ A, const f16* __restrict__ W,
    const float* __restrict__ bias, const float* __restrict__ scale,
    const int* __restrict__ cnt, const int* __restrict__ deg,
    float* __restrict__ C, float* __restrict__ Cadd, f16* __restrict__ Cf,
    const float* __restrict__ vs2, const float* __restrict__ vout2,
    const int* __restrict__ batch2, int K) {
  __shared__ f16 Ah[128 * 40];
  __shared__ f16 Wh[64 * 40];
  const int tid = threadIdx.x;
  const int row0 = blockIdx.x * 128, col0 = blockIdx.y * 64;
  const int lane = tid & 63;
  const int wave = tid >> 6;
  const int wr = (wave >> 1) * 64, wc = (wave & 1) * 32;
  const floatx4 fz = {0.f, 0.f, 0.f, 0.f};
  floatx4 acc[4][2];
#pragma unroll
  for (int m = 0; m < 4; m++)
#pragma unroll
    for (int n = 0; n < 2; n++) acc[m][n] = fz;
  const int q0 = tid * 2;
  const int rA0 = q0 >> 2, pA0 = q0 & 3;
  const int rA1 = (q0 + 1) >> 2, pA1 = (q0 + 1) & 3;
  const int rW = tid >> 2, pW = tid & 3;
  const int kb = (lane >> 4) * 8;
  const int fr = lane & 15;
  uint4 a0 = *reinterpret_cast<const uint4*>(&A[(size_t)(row0 + rA0) * K + pA0 * 8]);
  uint4 a1 = *reinterpret_cast<const uint4*>(&A[(size_t)(row0 + rA1) * K + pA1 * 8]);
  uint4 w0 = *reinterpret_cast<const uint4*>(&W[(size_t)(col0 + rW) * K + pW * 8]);
  for (int k0 = 0;;) {
    *reinterpret_cast<uint4*>(&Ah[rA0 * 40 + pA0 * 8]) = a0;
    *reinterpret_cast<uint4*>(&Ah[rA1 * 40 + pA1 * 8]) = a1;
    *reinterpret_cast<uint4*>(&Wh[rW * 40 + pW * 8]) = w0;
    __syncthreads();
    int kn = k0 + 32;
    if (kn < K) {
      a0 = *reinterpret_cast<const uint4*>(&A[(size_t)(row0 + rA0) * K + kn + pA0 * 8]);
      a1 = *reinterpret_cast<const uint4*>(&A[(size_t)(row0 + rA1) * K + kn + pA1 * 8]);
      w0 = *reinterpret_cast<const uint4*>(&W[(size_t)(col0 + rW) * K + kn + pW * 8]);
    }
    half8 af[4], wf[2];
#pragma unroll
    for (int m = 0; m < 4; m++)
      af[m] = *reinterpret_cast<const half8*>(&Ah[(wr + m * 16 + fr) * 40 + kb]);
#pragma unroll
    for (int n = 0; n < 2; n++)
      wf[n] = *reinterpret_cast<const half8*>(&Wh[(wc + n * 16 + fr) * 40 + kb]);
#pragma unroll
    for (int m = 0; m < 4; m++)
#pragma unroll
      for (int n = 0; n < 2; n++)
        acc[m][n] = __builtin_amdgcn_mfma_f32_16x16x32_f16(af[m], wf[n], acc[m][n], 0, 0, 0);
    if (kn >= K) break;
    __syncthreads();
    k0 = kn;
  }
  const int rl4 = (lane >> 4) * 4, cl = lane & 15;
#pragma unroll
  for (int m = 0; m < 4; m++) {
#pragma unroll
    for (int i = 0; i < 4; i++) {
      int row = row0 + wr + m * 16 + rl4 + i;
      float cb = (MODE == 4 || MODE == 5) ? (float)cnt[row] : 1.f;
      int dg = (MODE == 4 || MODE == 5) ? deg[row] : 0;
      int brow = (MODE == 7) ? batch2[row] : 0;
#pragma unroll
      for (int n = 0; n < 2; n++) {
        int col = col0 + wc + n * 16 + cl;
        float v = acc[m][n][i];
        size_t oi = (size_t)row * 256 + col;
        if (MODE == 4 || MODE == 5) {
          v += cb * bias[col];
          float sc = expf(scale[dg * 256 + col]);
          if (MODE == 4) Cadd[oi] += sc * v;
          else Cadd[oi] = sc * v;
          if (Cf) Cf[oi] = (f16)v;
        } else if (MODE == 7) {
          v += bias[col];
          float nv = C[oi] + Cadd[oi] + expf(vs2[col]) * vout2[(size_t)brow * 256 + col]
                   + expf(scale[col]) * v;
          Cf[oi] = (f16)nv;
        } else if (MODE == 6) {
          v += bias[col];
          float s1 = v, s2 = v * v;
#pragma unroll
          for (int o_ = 1; o_ < 16; o_ <<= 1) {
            s1 += __shfl_xor(s1, o_);
            s2 += __shfl_xor(s2, o_);
          }
          float mean = s1 * (1.f / 16.f);
          float var = s2 * (1.f / 16.f) - mean * mean;
          float gnv = (v - mean) * rsqrtf(var + 1e-5f);
          if (C) C[oi] = gnv;
          if (Cf) Cf[oi] = (f16)gnv;
        } else {
          if (bias) v += bias[col];
          if (C) C[oi] = v;
          if (Cf) Cf[oi] = (f16)v;
        }
      }
    }
  }
}

// ---------------- conv edge (CSR order): gather(fp16) + bond(global) + GN + fp16 glin ----------------
__global__ __launch_bounds__(256) void conv_edge_kernel(
    const f16* __restrict__ xp, const int* __restrict__ ea_s,
    const int* __restrict__ src_s, const int* __restrict__ dst_s,
    const float* __restrict__ bond_emb, const float* __restrict__ gate_w,
    const float* __restrict__ val_w, f16* __restrict__ msg) {
  constexpr int RS = 264;  // f16 row stride: 256 + 8 pad
  __shared__ f16 sg[16 * RS];
  __shared__ f16 sv[16 * RS];
  int tid = threadIdx.x;
  for (int i = tid; i < 4096; i += 256) {
    int g = i >> 8, rem = i & 255;
    sg[g * RS + rem] = (f16)gate_w[i];
    sv[g * RS + rem] = (f16)val_w[i];
  }
  __syncthreads();
  int idx = blockIdx.x * 256 + tid;
  int j = idx >> 4, g = idx & 15;
  int a0 = ea_s[j * 3 + 0], a1 = ea_s[j * 3 + 1], a2 = ea_s[j * 3 + 2];
  int d = dst_s[j], s = src_s[j];
  half8 xd0 = *reinterpret_cast<const half8*>(&xp[(size_t)d * 256 + g * 16]);
  half8 xd1 = *reinterpret_cast<const half8*>(&xp[(size_t)d * 256 + g * 16 + 8]);
  half8 xs0 = *reinterpret_cast<const half8*>(&xp[(size_t)s * 256 + g * 16]);
  half8 xs1 = *reinterpret_cast<const half8*>(&xp[(size_t)s * 256 + g * 16 + 8]);
  const float4* b0p = reinterpret_cast<const float4*>(&bond_emb[a0 * 256 + g * 16]);
  const float4* b1p = reinterpret_cast<const float4*>(&bond_emb[2048 + a1 * 256 + g * 16]);
  const float4* b2p = reinterpret_cast<const float4*>(&bond_emb[4096 + a2 * 256 + g * 16]);
  float xg[16], xv[16];
  float mg = 0.f, mv = 0.f;
#pragma unroll
  for (int q = 0; q < 4; q++) {
    float4 b0 = b0p[q], b1 = b1p[q], b2 = b2p[q];
#pragma unroll
    for (int t = 0; t < 4; t++) {
      int i = q * 4 + t;
      float bo = (&b0.x)[t] + (&b1.x)[t] + (&b2.x)[t];
      float xd = (i < 8) ? (float)xd0[i & 7] : (float)xd1[i & 7];
      float xs = (i < 8) ? (float)xs0[i & 7] : (float)xs1[i & 7];
      xg[i] = xd + bo;
      xv[i] = xs + bo;
      mg += xg[i];
      mv += xv[i];
    }
  }
  mg *= (1.f / 16.f);
  mv *= (1.f / 16.f);
  float vg = 0.f, vv = 0.f;
#pragma unroll
  for (int i = 0; i < 16; i++) {
    float dg_ = xg[i] - mg, dv_ = xv[i] - mv;
    vg += dg_ * dg_;
    vv += dv_ * dv_;
  }
  float rg = rsqrtf(vg * (1.f / 16.f) + 1e-5f);
  float rv = rsqrtf(vv * (1.f / 16.f) + 1e-5f);
#ifdef HAVE_FDOT2
  half2v xgh[8], xvh[8];
#pragma unroll
  for (int q = 0; q < 8; q++) {
    xgh[q][0] = (f16)((xg[2 * q] - mg) * rg);
    xgh[q][1] = (f16)((xg[2 * q + 1] - mg) * rg);
    xvh[q][0] = (f16)((xv[2 * q] - mv) * rv);
    xvh[q][1] = (f16)((xv[2 * q + 1] - mv) * rv);
  }
#else
#pragma unroll
  for (int i = 0; i < 16; i++) {
    xg[i] = (xg[i] - mg) * rg;
    xv[i] = (xv[i] - mv) * rv;
  }
#endif
  const f16* gRow = &sg[g * RS];
  const f16* vRow = &sv[g * RS];
  f16 res[16];
#pragma unroll
  for (int o = 0; o < 16; o++) {
    half8 gA = *reinterpret_cast<const half8*>(&gRow[o * 16]);
    half8 gB = *reinterpret_cast<const half8*>(&gRow[o * 16 + 8]);
    half8 vA = *reinterpret_cast<const half8*>(&vRow[o * 16]);
    half8 vB = *reinterpret_cast<const half8*>(&vRow[o * 16 + 8]);
    float ag = 0.f, av = 0.f;
#ifdef HAVE_FDOT2
#pragma unroll
    for (int q = 0; q < 4; q++) {
      half2v ga = {gA[2 * q], gA[2 * q + 1]};
      half2v gb = {gB[2 * q], gB[2 * q + 1]};
      half2v va = {vA[2 * q], vA[2 * q + 1]};
      half2v vb = {vB[2 * q], vB[2 * q + 1]};
      ag = __builtin_amdgcn_fdot2(xgh[q], ga, ag, false);
      ag = __builtin_amdgcn_fdot2(xgh[q + 4], gb, ag, false);
      av = __builtin_amdgcn_fdot2(xvh[q], va, av, false);
      av = __builtin_amdgcn_fdot2(xvh[q + 4], vb, av, false);
    }
#else
#pragma unroll
    for (int i = 0; i < 8; i++) {
      ag += xg[i] * (float)gA[i] + xg[i + 8] * (float)gB[i];
      av += xv[i] * (float)vA[i] + xv[i + 8] * (float)vB[i];
    }
#endif
    res[o] = (f16)(fmaxf(ag, 0.f) * av);
  }
  uint4* op = reinterpret_cast<uint4*>(&msg[(size_t)j * 256 + g * 16]);
  op[0] = reinterpret_cast<const uint4*>(res)[0];
  op[1] = reinterpret_cast<const uint4*>(res)[1];
}

// ---------------- glb middle (f16 input, pre-normalized): glin + relu*mul ----------------
template <int DOUT>
__global__ __launch_bounds__(256) void glb_mid_h_kernel(
    const f16* __restrict__ X, const float* __restrict__ gate_w,
    const float* __restrict__ val_w, f16* __restrict__ out) {
  constexpr int RS = DOUT * 16 + 8;
  __shared__ f16 sg[16 * RS];
  __shared__ f16 sv[16 * RS];
  int tid = threadIdx.x;
  for (int i = tid; i < 16 * DOUT * 16; i += 256) {
    int g = i / (DOUT * 16), rem = i % (DOUT * 16);
    sg[g * RS + rem] = (f16)gate_w[i];
    sv[g * RS + rem] = (f16)val_w[i];
  }
  __syncthreads();
  int idx = blockIdx.x * 256 + tid;
  int n = idx >> 4, g = idx & 15;
  half8 x0 = *reinterpret_cast<const half8*>(&X[(size_t)n * 256 + g * 16]);
  half8 x1 = *reinterpret_cast<const half8*>(&X[(size_t)n * 256 + g * 16 + 8]);
#ifdef HAVE_FDOT2
  half2v xh[8];
#pragma unroll
  for (int q = 0; q < 4; q++) {
    xh[q][0] = x0[2 * q]; xh[q][1] = x0[2 * q + 1];
    xh[q + 4][0] = x1[2 * q]; xh[q + 4][1] = x1[2 * q + 1];
  }
#else
  float x[16];
#pragma unroll
  for (int i = 0; i < 8; i++) { x[i] = (float)x0[i]; x[i + 8] = (float)x1[i]; }
#endif
  const f16* gRow = &sg[g * RS];
  const f16* vRow = &sv[g * RS];
  f16 res[DOUT];
#pragma unroll
  for (int o = 0; o < DOUT; o++) {
    half8 gA = *reinterpret_cast<const half8*>(&gRow[o * 16]);
    half8 gB = *reinterpret_cast<const half8*>(&gRow[o * 16 + 8]);
    half8 vA = *reinterpret_cast<const half8*>(&vRow[o * 16]);
    half8 vB = *reinterpret_cast<const half8*>(&vRow[o * 16 + 8]);
    float ag = 0.f, av = 0.f;
#ifdef HAVE_FDOT2
#pragma unroll
    for (int q = 0; q < 4; q++) {
      half2v gq = {gA[2 * q], gA[2 * q + 1]};
      half2v g2 = {gB[2 * q], gB[2 * q + 1]};
      half2v vq = {vA[2 * q], vA[2 * q + 1]};
      half2v v2 = {vB[2 * q], vB[2 * q + 1]};
      ag = __builtin_amdgcn_fdot2(xh[q], gq, ag, false);
      ag = __builtin_amdgcn_fdot2(xh[q + 4], g2, ag, false);
      av = __builtin_amdgcn_fdot2(xh[q], vq, av, false);
      av = __builtin_amdgcn_fdot2(xh[q + 4], v2, av, false);
    }
#else
#pragma unroll
    for (int i = 0; i < 8; i++) {
      ag += x[i] * (float)gA[i] + x[i + 8] * (float)gB[i];
      av += x[i] * (float)vA[i] + x[i + 8] * (float)vB[i];
    }
#endif
    res[o] = (f16)(fmaxf(ag, 0.f) * av);
  }
  f16* op = &out[(size_t)n * (16 * DOUT) + g * DOUT];
#pragma unroll
  for (int q = 0; q < DOUT / 8; q++)
    *reinterpret_cast<half8*>(&op[q * 8]) = *reinterpret_cast<const half8*>(&res[q * 8]);
}

// ---------------- fused VirtMessage ----------------
__global__ __launch_bounds__(256) void virt_fused_kernel(
    const float* __restrict__ h_in, const int* __restrict__ goff,
    const float* __restrict__ preW, const float* __restrict__ preb,
    const float* __restrict__ gateW, const float* __restrict__ valW,
    const float* __restrict__ postW, const float* __restrict__ postb,
    float* __restrict__ h_virt, float* __restrict__ vout) {
  __shared__ float sred[4][256];
  __shared__ float sx[256];
  __shared__ float xx[256];
  __shared__ float vv[512];
  int tid = threadIdx.x, b = blockIdx.x;
  int n0 = goff[b], n1 = goff[b + 1];
  int sub = tid >> 6, cg = tid & 63;
  float a0 = 0.f, a1 = 0.f, a2 = 0.f, a3 = 0.f;
  for (int n = n0 + sub; n < n1; n += 4) {
    float4 x = *reinterpret_cast<const float4*>(&h_in[(size_t)n * 256 + cg * 4]);
    a0 += x.x; a1 += x.y; a2 += x.z; a3 += x.w;
  }
  sred[sub][cg * 4 + 0] = a0;
  sred[sub][cg * 4 + 1] = a1;
  sred[sub][cg * 4 + 2] = a2;
  sred[sub][cg * 4 + 3] = a3;
  __syncthreads();
  float acc = h_virt[(size_t)b * 256 + tid] + sred[0][tid] + sred[1][tid] + sred[2][tid] + sred[3][tid];
  h_virt[(size_t)b * 256 + tid] = acc;
  sx[tid] = acc;
  __syncthreads();
  float dot = preb[tid];
  const float4* wrow = reinterpret_cast<const float4*>(&preW[(size_t)tid * 256]);
  const float4* sx4 = reinterpret_cast<const float4*>(sx);
#pragma unroll 8
  for (int q = 0; q < 64; q++) {
    float4 w = wrow[q];
    float4 s = sx4[q];
    dot += w.x * s.x + w.y * s.y + w.z * s.z + w.w * s.w;
  }
  float s1 = dot, s2 = dot * dot;
#pragma unroll
  for (int o_ = 1; o_ < 16; o_ <<= 1) {
    s1 += __shfl_xor(s1, o_);
    s2 += __shfl_xor(s2, o_);
  }
  float mean = s1 * (1.f / 16.f);
  float var = s2 * (1.f / 16.f) - mean * mean;
  xx[tid] = (dot - mean) * rsqrtf(var + 1e-5f);
  __syncthreads();
#pragma unroll
  for (int rep = 0; rep < 2; rep++) {
    int o = tid + rep * 256;
    int g = o >> 5, o2 = o & 31;
    const float4* gw = reinterpret_cast<const float4*>(&gateW[(size_t)(g * 32 + o2) * 16]);
    const float4* vw = reinterpret_cast<const float4*>(&valW[(size_t)(g * 32 + o2) * 16]);
    const float4* xg4 = reinterpret_cast<const float4*>(&xx[g * 16]);
    float ag = 0.f, av = 0.f;
#pragma unroll
    for (int q = 0; q < 4; q++) {
      float4 wg = gw[q], wv = vw[q], xq = xg4[q];
      ag += wg.x * xq.x + wg.y * xq.y + wg.z * xq.z + wg.w * xq.w;
      av += wv.x * xq.x + wv.y * xq.y + wv.z * xq.z + wv.w * xq.w;
    }
    vv[o] = fmaxf(ag, 0.f) * av;
  }
  __syncthreads();
  float outv = postb[tid];
  const float4* prow = reinterpret_cast<const float4*>(&postW[(size_t)tid * 512]);
  const float4* vv4 = reinterpret_cast<const float4*>(vv);
#pragma unroll 8
  for (int q = 0; q < 128; q++) {
    float4 w = prow[q], s = vv4[q];
    outv += w.x * s.x + w.y * s.y + w.z * s.z + w.w * s.w;
  }
  vout[(size_t)b * 256 + tid] = outv;
}

// ---------------- attention ----------------
// h_att layout: [b][h][head][v] = b*8192 + h*512 + head*16 + v
template <bool FIRST>
__global__ __launch_bounds__(256) void att_graph_kernel(
    const float* __restrict__ xv0, const float* __restrict__ k_w,
    const float* __restrict__ v_w, const int* __restrict__ goff,
    float* __restrict__ h_att, float* __restrict__ xk_sum) {
  __shared__ float kx[8][256];
  __shared__ float vx[8][256];
  __shared__ float rows[8][256];
  const int tid = threadIdx.x;
  const int b = blockIdx.x >> 1, half = blockIdx.x & 1;
  const int p = half * 256 + tid;
  const int g = p >> 5;
  const int headLocal = tid >> 4;
  const int head = p >> 4, h = p & 15;
  float wk[16], wv[16];
#pragma unroll
  for (int i = 0; i < 4; i++) {
    float4 k0 = *reinterpret_cast<const float4*>(&k_w[p * 16 + i * 4]);
    float4 v0 = *reinterpret_cast<const float4*>(&v_w[p * 16 + i * 4]);
    wk[i * 4 + 0] = k0.x; wk[i * 4 + 1] = k0.y; wk[i * 4 + 2] = k0.z; wk[i * 4 + 3] = k0.w;
    wv[i * 4 + 0] = v0.x; wv[i * 4 + 1] = v0.y; wv[i * 4 + 2] = v0.z; wv[i * 4 + 3] = v0.w;
  }
  float hacc[16];
  if (FIRST) {
#pragma unroll
    for (int j = 0; j < 16; j++) hacc[j] = 0.f;
  } else {
    const float* hg = &h_att[(size_t)b * 8192];
#pragma unroll
    for (int j = 0; j < 16; j++) hacc[j] = hg[h * 512 + head * 16 + j];
  }
  float ks = 0.f;
  const int n0 = goff[b], n1 = goff[b + 1];
  float r[8];
#pragma unroll
  for (int nn = 0; nn < 8; nn++) {
    int n = n0 + nn;
    r[nn] = (n < n1) ? xv0[(size_t)n * 256 + tid] : 0.f;
  }
  for (int nbase = n0; nbase < n1; nbase += 8) {
#pragma unroll
    for (int nn = 0; nn < 8; nn++) rows[nn][tid] = r[nn];
    __syncthreads();
#pragma unroll
    for (int nn = 0; nn < 8; nn++) {
      int n = nbase + 8 + nn;
      r[nn] = (n < n1) ? xv0[(size_t)n * 256 + tid] : 0.f;
    }
#pragma unroll
    for (int nn = 0; nn < 8; nn++) {
      const float4* rp = reinterpret_cast<const float4*>(&rows[nn][g * 16]);
      float aK = 0.f, aV = 0.f;
#pragma unroll
      for (int q = 0; q < 4; q++) {
        float4 x0 = rp[q];
#pragma unroll
        for (int t = 0; t < 4; t++) {
          float e0 = (&x0.x)[t];
          aK += e0 * wk[q * 4 + t];
          aV += e0 * wv[q * 4 + t];
        }
      }
      bool valid = (nbase + nn) < n1;
      float ek = valid ? expf(aK * 0.25f) : 0.f;
      kx[nn][tid] = ek;
      vx[nn][tid] = aV;
      ks += ek;
    }
    __syncthreads();
#pragma unroll
    for (int nn = 0; nn < 8; nn++) {
      float kk = kx[nn][tid];
      const float4* vp = reinterpret_cast<const float4*>(&vx[nn][headLocal * 16]);
#pragma unroll
      for (int q = 0; q < 4; q++) {
        float4 vq = vp[q];
        hacc[q * 4 + 0] += kk * vq.x;
        hacc[q * 4 + 1] += kk * vq.y;
        hacc[q * 4 + 2] += kk * vq.z;
        hacc[q * 4 + 3] += kk * vq.w;
      }
    }
    __syncthreads();
  }
  float* hgo = &h_att[(size_t)b * 8192];
#pragma unroll
  for (int j = 0; j < 16; j++) hgo[h * 512 + head * 16 + j] = hacc[j];
  xk_sum[(size_t)b * 512 + p] = ks;
}

// Per-graph att_out
__global__ __launch_bounds__(256) void att_out_kernel(
    const float* __restrict__ xv0, const float* __restrict__ q_w,
    const float* __restrict__ xk_sum, const float* __restrict__ h_att,
    const int* __restrict__ goff, f16* __restrict__ out) {
  __shared__ float sqw[16 * 260];
  __shared__ float hat[16 * 644];
  int tid = threadIdx.x, b = blockIdx.x;
  for (int i = tid; i < 8192; i += 256) {
    int g = i >> 9, rem = i & 511;
    sqw[g * 260 + rem] = q_w[i];
  }
  for (int i = tid; i < 8192; i += 256) {
    int h = i >> 9, rem = i & 511;
    int head = rem >> 4, v = rem & 15;
    hat[h * 644 + head * 20 + v] = h_att[(size_t)b * 8192 + i];
  }
  __syncthreads();
  int n0 = goff[b], n1 = goff[b + 1];
  int nl = tid >> 5, head = tid & 31;
  int g = head >> 1, j = head & 1;
  const float* ks = &xk_sum[(size_t)b * 512 + head * 16];
  for (int nbase = n0; nbase < n1; nbase += 8) {
    int n = nbase + nl;
    if (n >= n1) continue;
    float x[16];
    const float4* xp4 = reinterpret_cast<const float4*>(&xv0[(size_t)n * 256 + g * 16]);
#pragma unroll
    for (int q = 0; q < 4; q++) {
      float4 xq = xp4[q];
#pragma unroll
      for (int t = 0; t < 4; t++) x[q * 4 + t] = (&xq.x)[t];
    }
    float qv[16];
    float denom = 0.f;
#pragma unroll
    for (int h = 0; h < 16; h++) {
      const float4* wp = reinterpret_cast<const float4*>(&sqw[g * 260 + (j * 16 + h) * 16]);
      float a = 0.f;
#pragma unroll
      for (int q = 0; q < 4; q++) {
        float4 wq = wp[q];
#pragma unroll
        for (int t = 0; t < 4; t++) a += x[q * 4 + t] * (&wq.x)[t];
      }
      float e = expf(a * 0.25f);
      qv[h] = e;
      denom += e * ks[h];
    }
    float inv = 1.f / denom;
    float acc[16] = {0.f, 0.f, 0.f, 0.f, 0.f, 0.f, 0.f, 0.f,
                     0.f, 0.f, 0.f, 0.f, 0.f, 0.f, 0.f, 0.f};
#pragma unroll
    for (int h = 0; h < 16; h++) {
      float qh = qv[h];
      const float4* hp = reinterpret_cast<const float4*>(&hat[h * 644 + head * 20]);
#pragma unroll
      for (int q = 0; q < 4; q++) {
        float4 vq = hp[q];
        acc[q * 4 + 0] += qh * vq.x;
        acc[q * 4 + 1] += qh * vq.y;
        acc[q * 4 + 2] += qh * vq.z;
        acc[q * 4 + 3] += qh * vq.w;
      }
    }
    f16 res[16];
#pragma unroll
    for (int v = 0; v < 16; v++) res[v] = (f16)(acc[v] * inv);
    uint4* op = reinterpret_cast<uint4*>(&out[(size_t)n * 512 + head * 16]);
    op[0] = reinterpret_cast<const uint4*>(res)[0];
    op[1] = reinterpret_cast<const uint4*>(res)[1];
  }
}

// ---------------- host driver ----------------

extern "C" void kernel_launch(void* const* d_in, const int* in_sizes, int n_in,
                              void* d_out, int out_size, void* d_ws, size_t ws_size,
                              hipStream_t stream) {
  const int* x_feat = (const int*)d_in[0];
  const int* eidx = (const int*)d_in[1];
  const int* eattr = (const int*)d_in[2];
  const int* batch = (const int*)d_in[3];
  const float* edist = (const float*)d_in[5];
  const float* atom_emb = (const float*)d_in[6];
  const float* bond2d = (const float*)d_in[7];
  const float* gmeans = (const float*)d_in[8];
  const float* gstds = (const float*)d_in[9];
  const float* attn_w = (const float*)d_in[10];
  const float* attn_b = (const float*)d_in[11];
  const float* scale_both = (const float*)d_in[12];
  const float* conv_bond_emb = (const float*)d_in[13];
  const float* conv_pre_w = (const float*)d_in[14];
  const float* conv_gate_w = (const float*)d_in[15];
  const float* conv_val_w = (const float*)d_in[16];
  const float* conv_post_w = (const float*)d_in[17];
  const float* conv_post_b = (const float*)d_in[18];
  const float* conv_scale = (const float*)d_in[19];
  const float* virt_pre_w = (const float*)d_in[20];
  const float* virt_pre_b = (const float*)d_in[21];
  const float* virt_gate_w = (const float*)d_in[22];
  const float* virt_val_w = (const float*)d_in[23];
  const float* virt_post_w = (const float*)d_in[24];
  const float* virt_post_b = (const float*)d_in[25];
  const float* virt_scale = (const float*)d_in[26];
  const float* att_pre_w = (const float*)d_in[27];
  const float* att_pre_b = (const float*)d_in[28];
  const float* att_q_w = (const float*)d_in[29];
  const float* att_k_w = (const float*)d_in[30];
  const float* att_v_w = (const float*)d_in[31];
  const float* att_post_w = (const float*)d_in[32];
  const float* att_post_b = (const float*)d_in[33];
  const float* att_scale = (const float*)d_in[34];
  const float* main_pre_w = (const float*)d_in[35];
  const float* main_pre_b = (const float*)d_in[36];
  const float* main_gate_w = (const float*)d_in[37];
  const float* main_val_w = (const float*)d_in[38];
  const float* main_post_w = (const float*)d_in[39];
  const float* main_post_b = (const float*)d_in[40];

  const int* src = eidx;
  const int* dst = eidx + EE;

  float* ws = (float*)d_ws;
  float* h_in = ws;
  float* x_out = ws + ND;
  float* nodeA = ws + 2 * ND;
  f16* h_inH = (f16*)(ws + 3 * ND);
  f16* xrawH = (f16*)(ws + 3 * ND + ND / 2);
  f16* hTmp = (f16*)(ws + 4 * ND);
  f16* gnH = (f16*)(ws + 4 * ND + ND / 2);
  f16* msgH = (f16*)(ws + 5 * ND);            // 3*ND halfs
  float* sm = ws + 7 * ND;
  f16* hW = (f16*)sm;                          // weights fp16 pool
  float* h_virt = sm + 1179648;
  float* h_att = h_virt + 65536;
  float* xk_sum = h_att + 2097152;
  float* vout = xk_sum + 131072;               // B*256
  int* cnt = (int*)(vout + 65536);
  int* deg = cnt + NN;
  int* goff = deg + NN;
  int* off = goff + BB + 1;
  int* cursor = off + NN + 1;
  int* elist = cursor + NN;
  int* ea_s = elist + EE;
  int* src_s = ea_s + 3 * EE;
  int* dst_s = src_s + EE;
  float* ed_s = (float*)(dst_s + EE);

  f16* wCpre = hW;
  f16* wCpost = hW + 524288;
  f16* wApre = hW + 1048576;
  f16* wApost = hW + 1179648;
  f16* wMpre = hW + 1441792;
  f16* wMpost = hW + 1572864;

  auto cvt = [&](const float* in, f16* out, int n) {
    f2h_kernel<<<n / 4 / 256, 256, 0, stream>>>(in, out, n / 4);
  };

  cvt(conv_pre_w, wCpre, 524288);
  cvt(conv_post_w, wCpost, 524288);
  cvt(att_pre_w, wApre, 131072);
  cvt(att_post_w, wApost, 262144);
  cvt(main_pre_w, wMpre, 131072);
  cvt(main_post_w, wMpost, 393216);

  // degree + graph offsets + CSR + gathered edge data
  (void)hipMemsetAsync(cnt, 0, NN * sizeof(int), stream);
  count_deg_kernel<<<EE / 256, 256, 0, stream>>>(dst, cnt, EE);
  clip_deg_kernel<<<NN / 256, 256, 0, stream>>>(cnt, deg, NN);
  goff_kernel<<<(NN + 256) / 256, 256, 0, stream>>>(batch, goff, NN, BB);
  scan_off_kernel<<<1, 256, 0, stream>>>(cnt, off);
  copy_i_kernel<<<NN / 256, 256, 0, stream>>>(off, cursor, NN);
  fill_elist_kernel<<<EE / 256, 256, 0, stream>>>(dst, cursor, elist, EE);
  gather_edges_kernel<<<EE / 256, 256, 0, stream>>>(elist, eattr, src, dst, edist,
                                                    ea_s, src_s, dst_s, ed_s);

  // initial node features
  edge_feat_kernel<<<EE / 4, 256, 0, stream>>>(ea_s, ed_s, bond2d, gmeans, gstds,
                                               attn_w, attn_b, msgH);
  seg_reduce_kernel<float><<<NN / 4, 256, 0, stream>>>(msgH, off, x_out);
  atom_finish_kernel<<<NN * 64 / 256, 256, 0, stream>>>(x_feat, atom_emb, scale_both, deg,
                                                        x_out, h_in, h_inH);
  (void)hipMemsetAsync(h_virt, 0, 65536 * 4, stream);

  const dim3 gN(NN / 128, 4);
  const int n4 = (int)(ND / 4);

  for (int l = 0; l < 2; l++) {
    // ---- ConvMessage ----
    const f16* curH = h_inH;
    for (int k = 0; k < 4; k++) {
      if (k == 2) {
        add3h_kernel<<<n4 / 256, 256, 0, stream>>>(xrawH, h_in, x_out, n4);
        curH = xrawH;
      }
      size_t lk = (size_t)(l * 4 + k);
      hgemm_kernel<0><<<gN, 256, 0, stream>>>(curH, wCpre + lk * 65536, nullptr, nullptr,
                                              nullptr, nullptr, nullptr, nullptr, hTmp,
                                              nullptr, nullptr, nullptr, 256);
      conv_edge_kernel<<<EE * 16 / 256, 256, 0, stream>>>(
          hTmp, ea_s, src_s, dst_s, conv_bond_emb + lk * 6144,
          conv_gate_w + lk * 4096, conv_val_w + lk * 4096, msgH);
      seg_reduce_kernel<f16><<<NN / 4, 256, 0, stream>>>(msgH, off, gnH);
      if (k == 0 || k == 2)
        hgemm_kernel<5><<<gN, 256, 0, stream>>>(gnH, wCpost + lk * 65536,
                                                conv_post_b + lk * 256, conv_scale + lk * 1024,
                                                cnt, deg, nullptr, x_out, xrawH,
                                                nullptr, nullptr, nullptr, 256);
      else
        hgemm_kernel<4><<<gN, 256, 0, stream>>>(gnH, wCpost + lk * 65536,
                                                conv_post_b + lk * 256, conv_scale + lk * 1024,
                                                cnt, deg, nullptr, x_out, xrawH,
                                                nullptr, nullptr, nullptr, 256);
      curH = xrawH;
    }
    // h_out = h_in + x_out folded into MODE 7 epilogue below.

    // ---- VirtMessage (fused) ----
    virt_fused_kernel<<<BB, 256, 0, stream>>>(
        h_in, goff, virt_pre_w + (size_t)l * 65536, virt_pre_b + (size_t)l * 256,
        virt_gate_w + (size_t)l * 8192, virt_val_w + (size_t)l * 8192,
        virt_post_w + (size_t)l * 131072, virt_post_b + (size_t)l * 256, h_virt, vout);

    // ---- AttMessage ----
    hgemm_kernel<6><<<gN, 256, 0, stream>>>(h_inH, wApre + (size_t)l * 65536,
                                            att_pre_b + (size_t)l * 256, nullptr, nullptr,
                                            nullptr, nodeA, nullptr, nullptr,
                                            nullptr, nullptr, nullptr, 256);
    if (l == 0)
      att_graph_kernel<true><<<BB * 2, 256, 0, stream>>>(
          nodeA, att_k_w + (size_t)l * 8192, att_v_w + (size_t)l * 8192, goff, h_att, xk_sum);
    else
      att_graph_kernel<false><<<BB * 2, 256, 0, stream>>>(
          nodeA, att_k_w + (size_t)l * 8192, att_v_w + (size_t)l * 8192, goff, h_att, xk_sum);
    att_out_kernel<<<BB, 256, 0, stream>>>(
        nodeA, att_q_w + (size_t)l * 8192, xk_sum, h_att, goff, msgH);
    // hTmp = f16(h_in + x_out + exp(vs)*vout[batch] + exp(as)*attpost)
    hgemm_kernel<7><<<gN, 256, 0, stream>>>(msgH, wApost + (size_t)l * 131072,
                                            att_post_b + (size_t)l * 256,
                                            att_scale + (size_t)l * 256, nullptr, nullptr,
                                            h_in, x_out, hTmp,
                                            virt_scale + (size_t)l * 256, vout, batch, 512);

    // ---- main gated block ----
    hgemm_kernel<6><<<gN, 256, 0, stream>>>(hTmp, wMpre + (size_t)l * 65536,
                                            main_pre_b + (size_t)l * 256, nullptr, nullptr,
                                            nullptr, nullptr, nullptr, gnH,
                                            nullptr, nullptr, nullptr, 256);
    glb_mid_h_kernel<48><<<NN * 16 / 256, 256, 0, stream>>>(
        gnH, main_gate_w + (size_t)l * 12288, main_val_w + (size_t)l * 12288, msgH);
    float* hdst = (l == 1) ? (float*)d_out : h_in;
    f16* hdstH = (l == 1) ? nullptr : h_inH;
    hgemm_kernel<0><<<gN, 256, 0, stream>>>(msgH, wMpost + (size_t)l * 196608,
                                            main_post_b + (size_t)l * 256, nullptr, nullptr,
                                            nullptr, hdst, nullptr, hdstH,
                                            nullptr, nullptr, nullptr, 768);
  }
}

// Round 17
// 909.200 us; speedup vs baseline: 1.5350x; 1.0711x over previous
//
#include <hip/hip_runtime.h>
#include <cstdint>
#include <cstddef>
#include <type_traits>

#define NN 16384
#define EE 49152
#define BB 256
// D=256, G=16, 16 channels per group, HD=16

typedef _Float16 f16;
typedef _Float16 half8 __attribute__((ext_vector_type(8)));
typedef _Float16 half4v __attribute__((ext_vector_type(4)));
typedef _Float16 half2v __attribute__((ext_vector_type(2)));
typedef float floatx4 __attribute__((ext_vector_type(4)));

#if defined(__has_builtin)
#if __has_builtin(__builtin_amdgcn_fdot2)
#define HAVE_FDOT2 1
#endif
#endif

static constexpr size_t ND = (size_t)NN * 256;

// ---------------- setup kernels ----------------

__global__ __launch_bounds__(256) void count_deg_kernel(const int* __restrict__ dst, int* __restrict__ cnt, int e) {
  int i = blockIdx.x * 256 + threadIdx.x;
  if (i < e) atomicAdd(&cnt[dst[i]], 1);
}
__global__ __launch_bounds__(256) void clip_deg_kernel(const int* __restrict__ cnt, int* __restrict__ deg, int n) {
  int i = blockIdx.x * 256 + threadIdx.x;
  if (i < n) { int v = cnt[i] - 1; deg[i] = v < 0 ? 0 : (v > 3 ? 3 : v); }
}
__global__ __launch_bounds__(256) void goff_kernel(const int* __restrict__ batch, int* __restrict__ goff, int n, int b) {
  int i = blockIdx.x * 256 + threadIdx.x;
  if (i > n) return;
  int cur = (i < n) ? batch[i] : b;
  int prev = (i == 0) ? -1 : batch[i - 1];
  for (int x = prev + 1; x <= cur; x++) goff[x] = i;
}
__global__ __launch_bounds__(256) void scan_off_kernel(const int* __restrict__ cnt, int* __restrict__ off) {
  __shared__ int part[256];
  int tid = threadIdx.x;
  int base = tid * 64;
  int s = 0;
  for (int i = 0; i < 64; i++) s += cnt[base + i];
  part[tid] = s;
  __syncthreads();
  for (int o = 1; o < 256; o <<= 1) {
    int t = (tid >= o) ? part[tid - o] : 0;
    __syncthreads();
    part[tid] += t;
    __syncthreads();
  }
  int run = (tid == 0) ? 0 : part[tid - 1];
  for (int i = 0; i < 64; i++) {
    off[base + i] = run;
    run += cnt[base + i];
  }
  if (tid == 255) off[NN] = run;
}
__global__ __launch_bounds__(256) void copy_i_kernel(const int* __restrict__ a, int* __restrict__ b, int n) {
  int i = blockIdx.x * 256 + threadIdx.x;
  if (i < n) b[i] = a[i];
}
__global__ __launch_bounds__(256) void fill_elist_kernel(const int* __restrict__ dst,
    int* __restrict__ cursor, int* __restrict__ elist, int e) {
  int i = blockIdx.x * 256 + threadIdx.x;
  if (i < e) {
    int p = atomicAdd(&cursor[dst[i]], 1);
    elist[p] = i;
  }
}
// gather edge data into CSR (dst-sorted) order
__global__ __launch_bounds__(256) void gather_edges_kernel(const int* __restrict__ elist,
    const int* __restrict__ eattr, const int* __restrict__ src, const int* __restrict__ dst,
    const float* __restrict__ edist, int* __restrict__ ea_s, int* __restrict__ src_s,
    int* __restrict__ dst_s, float* __restrict__ ed_s) {
  int j = blockIdx.x * 256 + threadIdx.x;
  if (j >= EE) return;
  int e = elist[j];
  ea_s[j * 3 + 0] = eattr[e * 3 + 0];
  ea_s[j * 3 + 1] = eattr[e * 3 + 1];
  ea_s[j * 3 + 2] = eattr[e * 3 + 2];
  src_s[j] = src[e];
  dst_s[j] = dst[e];
  ed_s[j] = edist[e];
}
// dstH = f16(a + b)
__global__ __launch_bounds__(256) void add3h_kernel(f16* __restrict__ dstH,
    const float* __restrict__ a, const float* __restrict__ b, int n4) {
  int i = blockIdx.x * 256 + threadIdx.x;
  if (i >= n4) return;
  float4 x = reinterpret_cast<const float4*>(a)[i];
  float4 y = reinterpret_cast<const float4*>(b)[i];
  half4v h;
  h[0] = (f16)(x.x + y.x); h[1] = (f16)(x.y + y.y);
  h[2] = (f16)(x.z + y.z); h[3] = (f16)(x.w + y.w);
  reinterpret_cast<half4v*>(dstH)[i] = h;
}
// one-shot conversion of all 6 weight tensors (region table hardcoded, float4 units)
__global__ __launch_bounds__(256) void cvt6_kernel(
    const float* __restrict__ s0, const float* __restrict__ s1, const float* __restrict__ s2,
    const float* __restrict__ s3, const float* __restrict__ s4, const float* __restrict__ s5,
    f16* __restrict__ d0, f16* __restrict__ d1, f16* __restrict__ d2,
    f16* __restrict__ d3, f16* __restrict__ d4, f16* __restrict__ d5) {
  int i = blockIdx.x * 256 + threadIdx.x;  // float4 index, total 491520
  const float* s;
  f16* d;
  int local;
  if (i < 131072)       { s = s0; d = d0; local = i; }
  else if (i < 262144)  { s = s1; d = d1; local = i - 131072; }
  else if (i < 294912)  { s = s2; d = d2; local = i - 262144; }
  else if (i < 360448)  { s = s3; d = d3; local = i - 294912; }
  else if (i < 393216)  { s = s4; d = d4; local = i - 360448; }
  else                  { s = s5; d = d5; local = i - 393216; }
  float4 v = reinterpret_cast<const float4*>(s)[local];
  half4v o;
  o[0] = (f16)v.x; o[1] = (f16)v.y; o[2] = (f16)v.z; o[3] = (f16)v.w;
  reinterpret_cast<half4v*>(d)[local] = o;
}

// ---------------- segment reduce over CONTIGUOUS CSR rows ----------------
template <typename OUT>
__global__ __launch_bounds__(256) void seg_reduce_kernel(const f16* __restrict__ msg,
    const int* __restrict__ off, OUT* __restrict__ out) {
  int idx = blockIdx.x * 256 + threadIdx.x;
  int n = idx >> 6, c0 = (idx & 63) * 4;
  int j0 = off[n], j1 = off[n + 1];
  float a0 = 0.f, a1 = 0.f, a2 = 0.f, a3 = 0.f;
  int j = j0;
  for (; j + 1 < j1; j += 2) {
    half4v m0 = *reinterpret_cast<const half4v*>(&msg[(size_t)j * 256 + c0]);
    half4v m1 = *reinterpret_cast<const half4v*>(&msg[(size_t)(j + 1) * 256 + c0]);
    a0 += (float)m0[0] + (float)m1[0];
    a1 += (float)m0[1] + (float)m1[1];
    a2 += (float)m0[2] + (float)m1[2];
    a3 += (float)m0[3] + (float)m1[3];
  }
  if (j < j1) {
    half4v m0 = *reinterpret_cast<const half4v*>(&msg[(size_t)j * 256 + c0]);
    a0 += (float)m0[0]; a1 += (float)m0[1]; a2 += (float)m0[2]; a3 += (float)m0[3];
  }
  if constexpr (std::is_same<OUT, float>::value) {
    float4 o = {a0, a1, a2, a3};
    *reinterpret_cast<float4*>(&out[(size_t)n * 256 + c0]) = o;
  } else {
    half4v o;
    o[0] = (f16)a0; o[1] = (f16)a1; o[2] = (f16)a2; o[3] = (f16)a3;
    *reinterpret_cast<half4v*>(&out[(size_t)n * 256 + c0]) = o;
  }
}

// ---------------- initial edge / node features (CSR order) ----------------

__global__ __launch_bounds__(256) void edge_feat_kernel(
    const int* __restrict__ ea_s, const float* __restrict__ ed_s,
    const float* __restrict__ bond2d, const float* __restrict__ gmeans,
    const float* __restrict__ gstds, const float* __restrict__ attn_w,
    const float* __restrict__ attn_b, f16* __restrict__ msg) {
  int lane = threadIdx.x & 63;
  int j = blockIdx.x * 4 + (threadIdx.x >> 6);
  if (j >= EE) return;
  int a0 = ea_s[j * 3 + 0], a1 = ea_s[j * 3 + 1], a2 = ea_s[j * 3 + 2];
  float dist = ed_s[j];
  const float SQ2PI = sqrtf(2.0f * 3.14159f);
  int c0 = lane * 4;
  float4 b0 = *reinterpret_cast<const float4*>(&bond2d[a0 * 256 + c0]);
  float4 b1 = *reinterpret_cast<const float4*>(&bond2d[2048 + a1 * 256 + c0]);
  float4 b2 = *reinterpret_cast<const float4*>(&bond2d[4096 + a2 * 256 + c0]);
  float4 gm = *reinterpret_cast<const float4*>(&gmeans[c0]);
  float4 gs = *reinterpret_cast<const float4*>(&gstds[c0]);
  float4 w2 = *reinterpret_cast<const float4*>(&attn_w[c0]);
  float4 w3 = *reinterpret_cast<const float4*>(&attn_w[256 + c0]);
  float h2[4], h3[4];
  float part = 0.f;
#pragma unroll
  for (int i = 0; i < 4; i++) {
    h2[i] = (&b0.x)[i] + (&b1.x)[i] + (&b2.x)[i];
    float sd = fabsf((&gs.x)[i]) + 0.01f;
    float df = (dist - (&gm.x)[i]) / sd;
    h3[i] = expf(-0.5f * df * df) / (SQ2PI * sd);
    part += (&w2.x)[i] * h2[i] + (&w3.x)[i] * h3[i];
  }
#pragma unroll
  for (int off = 32; off > 0; off >>= 1) part += __shfl_xor(part, off);
  float wg = 1.f / (1.f + expf(-(part + attn_b[0])));
  half4v o;
#pragma unroll
  for (int i = 0; i < 4; i++) o[i] = (f16)(wg * h2[i] + (1.f - wg) * h3[i]);
  *reinterpret_cast<half4v*>(&msg[(size_t)j * 256 + c0]) = o;
}

__global__ __launch_bounds__(256) void atom_finish_kernel(
    const int* __restrict__ xf, const float* __restrict__ emb,
    const float* __restrict__ scale_both, const int* __restrict__ deg,
    const float* __restrict__ tmp, float* __restrict__ h_in, f16* __restrict__ h_inH) {
  int idx = blockIdx.x * 256 + threadIdx.x;
  int n = idx >> 6, c = (idx & 63) * 4;
  float a0 = 0.f, a1 = 0.f, a2 = 0.f, a3 = 0.f;
#pragma unroll
  for (int f = 0; f < 9; f++) {
    int v = xf[n * 9 + f];
    float4 e = *reinterpret_cast<const float4*>(&emb[((size_t)(f * 128 + v)) * 256 + c]);
    a0 += e.x; a1 += e.y; a2 += e.z; a3 += e.w;
  }
  int dg = deg[n];
  float4 s = *reinterpret_cast<const float4*>(&scale_both[dg * 256 + c]);
  float4 t = *reinterpret_cast<const float4*>(&tmp[(size_t)n * 256 + c]);
  float4 r;
  r.x = a0 + expf(s.x) * t.x; r.y = a1 + expf(s.y) * t.y;
  r.z = a2 + expf(s.z) * t.z; r.w = a3 + expf(s.w) * t.w;
  *reinterpret_cast<float4*>(&h_in[(size_t)n * 256 + c]) = r;
  half4v h;
  h[0] = (f16)r.x; h[1] = (f16)r.y; h[2] = (f16)r.z; h[3] = (f16)r.w;
  *reinterpret_cast<half4v*>(&h_inH[(size_t)n * 256 + c]) = h;
}

// ---------------- fp16 MFMA GEMM, tile 64x64, 4 waves (2x2 of 32x32), BK=32, reg prefetch ----------------
// MODE 0: v=acc(+bias); C?=v; Cf?=f16(v)
// MODE 4: v=acc+cnt[row]*bias[col]; Cadd[oi]+=expf(scale[deg[row]*256+col])*v; Cf?=f16(v)
// MODE 5: like 4 but Cadd[oi]= (init store)
// MODE 6: v=acc+bias; GroupNorm per 16-col group (16-lane shuffles); C?=gn; Cf?=f16(gn)
// MODE 7: v=acc+bias; nv=C[oi]+Cadd[oi] + expf(vs2[col])*vout2[batch2[row]*256+col] + expf(scale[col])*v; Cf=f16(nv)
template <int MODE>
__global__ __launch_bounds__(256) void hgemm_kernel(
    const f16* __restrict__ A, const f16* __restrict__ W,
    const float* __restrict__ bias, const float* __restrict__ scale,
    const int* __restrict__ cnt, const int* __restrict__ deg,
    float* __restrict__ C, float* __restrict__ Cadd, f16* __restrict__ Cf,
    const float* __restrict__ vs2, const float* __restrict__ vout2,
    const int* __restrict__ batch2, int K) {
  __shared__ f16 Ah[64 * 40];
  __shared__ f16 Wh[64 * 40];
  const int tid = threadIdx.x;
  const int row0 = blockIdx.x * 64, col0 = blockIdx.y * 64;
  const int lane = tid & 63;
  const int wave = tid >> 6;
  const int wr = (wave >> 1) * 32, wc = (wave & 1) * 32;
  const floatx4 fz = {0.f, 0.f, 0.f, 0.f};
  floatx4 acc[2][2];
#pragma unroll
  for (int m = 0; m < 2; m++)
#pragma unroll
    for (int n = 0; n < 2; n++) acc[m][n] = fz;
  const int rS = tid >> 2, pS = tid & 3;  // 256 chunks: row tid/4, 8-half part tid%4
  const int kb = (lane >> 4) * 8;
  const int fr = lane & 15;
  uint4 a0 = *reinterpret_cast<const uint4*>(&A[(size_t)(row0 + rS) * K + pS * 8]);
  uint4 w0 = *reinterpret_cast<const uint4*>(&W[(size_t)(col0 + rS) * K + pS * 8]);
  for (int k0 = 0;;) {
    *reinterpret_cast<uint4*>(&Ah[rS * 40 + pS * 8]) = a0;
    *reinterpret_cast<uint4*>(&Wh[rS * 40 + pS * 8]) = w0;
    __syncthreads();
    int kn = k0 + 32;
    if (kn < K) {
      a0 = *reinterpret_cast<const uint4*>(&A[(size_t)(row0 + rS) * K + kn + pS * 8]);
      w0 = *reinterpret_cast<const uint4*>(&W[(size_t)(col0 + rS) * K + kn + pS * 8]);
    }
    half8 af[2], wf[2];
#pragma unroll
    for (int m = 0; m < 2; m++)
      af[m] = *reinterpret_cast<const half8*>(&Ah[(wr + m * 16 + fr) * 40 + kb]);
#pragma unroll
    for (int n = 0; n < 2; n++)
      wf[n] = *reinterpret_cast<const half8*>(&Wh[(wc + n * 16 + fr) * 40 + kb]);
#pragma unroll
    for (int m = 0; m < 2; m++)
#pragma unroll
      for (int n = 0; n < 2; n++)
        acc[m][n] = __builtin_amdgcn_mfma_f32_16x16x32_f16(af[m], wf[n], acc[m][n], 0, 0, 0);
    if (kn >= K) break;
    __syncthreads();
    k0 = kn;
  }
  const int rl4 = (lane >> 4) * 4, cl = lane & 15;
#pragma unroll
  for (int m = 0; m < 2; m++) {
#pragma unroll
    for (int i = 0; i < 4; i++) {
      int row = row0 + wr + m * 16 + rl4 + i;
      float cb = (MODE == 4 || MODE == 5) ? (float)cnt[row] : 1.f;
      int dg = (MODE == 4 || MODE == 5) ? deg[row] : 0;
      int brow = (MODE == 7) ? batch2[row] : 0;
#pragma unroll
      for (int n = 0; n < 2; n++) {
        int col = col0 + wc + n * 16 + cl;
        float v = acc[m][n][i];
        size_t oi = (size_t)row * 256 + col;
        if (MODE == 4 || MODE == 5) {
          v += cb * bias[col];
          float sc = expf(scale[dg * 256 + col]);
          if (MODE == 4) Cadd[oi] += sc * v;
          else Cadd[oi] = sc * v;
          if (Cf) Cf[oi] = (f16)v;
        } else if (MODE == 7) {
          v += bias[col];
          float nv = C[oi] + Cadd[oi] + expf(vs2[col]) * vout2[(size_t)brow * 256 + col]
                   + expf(scale[col]) * v;
          Cf[oi] = (f16)nv;
        } else if (MODE == 6) {
          v += bias[col];
          float s1 = v, s2 = v * v;
#pragma unroll
          for (int o_ = 1; o_ < 16; o_ <<= 1) {
            s1 += __shfl_xor(s1, o_);
            s2 += __shfl_xor(s2, o_);
          }
          float mean = s1 * (1.f / 16.f);
          float var = s2 * (1.f / 16.f) - mean * mean;
          float gnv = (v - mean) * rsqrtf(var + 1e-5f);
          if (C) C[oi] = gnv;
          if (Cf) Cf[oi] = (f16)gnv;
        } else {
          if (bias) v += bias[col];
          if (C) C[oi] = v;
          if (Cf) Cf[oi] = (f16)v;
        }
      }
    }
  }
}

// ---------------- conv edge (CSR order): gather(fp16) + bond(global) + GN + fp16 glin ----------------
__global__ __launch_bounds__(256) void conv_edge_kernel(
    const f16* __restrict__ xp, const int* __restrict__ ea_s,
    const int* __restrict__ src_s, const int* __restrict__ dst_s,
    const float* __restrict__ bond_emb, const float* __restrict__ gate_w,
    const float* __restrict__ val_w, f16* __restrict__ msg) {
  constexpr int RS = 264;  // f16 row stride: 256 + 8 pad
  __shared__ f16 sg[16 * RS];
  __shared__ f16 sv[16 * RS];
  int tid = threadIdx.x;
  for (int i = tid; i < 4096; i += 256) {
    int g = i >> 8, rem = i & 255;
    sg[g * RS + rem] = (f16)gate_w[i];
    sv[g * RS + rem] = (f16)val_w[i];
  }
  __syncthreads();
  int idx = blockIdx.x * 256 + tid;
  int j = idx >> 4, g = idx & 15;
  int a0 = ea_s[j * 3 + 0], a1 = ea_s[j * 3 + 1], a2 = ea_s[j * 3 + 2];
  int d = dst_s[j], s = src_s[j];
  half8 xd0 = *reinterpret_cast<const half8*>(&xp[(size_t)d * 256 + g * 16]);
  half8 xd1 = *reinterpret_cast<const half8*>(&xp[(size_t)d * 256 + g * 16 + 8]);
  half8 xs0 = *reinterpret_cast<const half8*>(&xp[(size_t)s * 256 + g * 16]);
  half8 xs1 = *reinterpret_cast<const half8*>(&xp[(size_t)s * 256 + g * 16 + 8]);
  const float4* b0p = reinterpret_cast<const float4*>(&bond_emb[a0 * 256 + g * 16]);
  const float4* b1p = reinterpret_cast<const float4*>(&bond_emb[2048 + a1 * 256 + g * 16]);
  const float4* b2p = reinterpret_cast<const float4*>(&bond_emb[4096 + a2 * 256 + g * 16]);
  float xg[16], xv[16];
  float mg = 0.f, mv = 0.f;
#pragma unroll
  for (int q = 0; q < 4; q++) {
    float4 b0 = b0p[q], b1 = b1p[q], b2 = b2p[q];
#pragma unroll
    for (int t = 0; t < 4; t++) {
      int i = q * 4 + t;
      float bo = (&b0.x)[t] + (&b1.x)[t] + (&b2.x)[t];
      float xd = (i < 8) ? (float)xd0[i & 7] : (float)xd1[i & 7];
      float xs = (i < 8) ? (float)xs0[i & 7] : (float)xs1[i & 7];
      xg[i] = xd + bo;
      xv[i] = xs + bo;
      mg += xg[i];
      mv += xv[i];
    }
  }
  mg *= (1.f / 16.f);
  mv *= (1.f / 16.f);
  float vg = 0.f, vv = 0.f;
#pragma unroll
  for (int i = 0; i < 16; i++) {
    float dg_ = xg[i] - mg, dv_ = xv[i] - mv;
    vg += dg_ * dg_;
    vv += dv_ * dv_;
  }
  float rg = rsqrtf(vg * (1.f / 16.f) + 1e-5f);
  float rv = rsqrtf(vv * (1.f / 16.f) + 1e-5f);
#ifdef HAVE_FDOT2
  half2v xgh[8], xvh[8];
#pragma unroll
  for (int q = 0; q < 8; q++) {
    xgh[q][0] = (f16)((xg[2 * q] - mg) * rg);
    xgh[q][1] = (f16)((xg[2 * q + 1] - mg) * rg);
    xvh[q][0] = (f16)((xv[2 * q] - mv) * rv);
    xvh[q][1] = (f16)((xv[2 * q + 1] - mv) * rv);
  }
#else
#pragma unroll
  for (int i = 0; i < 16; i++) {
    xg[i] = (xg[i] - mg) * rg;
    xv[i] = (xv[i] - mv) * rv;
  }
#endif
  const f16* gRow = &sg[g * RS];
  const f16* vRow = &sv[g * RS];
  f16 res[16];
#pragma unroll
  for (int o = 0; o < 16; o++) {
    half8 gA = *reinterpret_cast<const half8*>(&gRow[o * 16]);
    half8 gB = *reinterpret_cast<const half8*>(&gRow[o * 16 + 8]);
    half8 vA = *reinterpret_cast<const half8*>(&vRow[o * 16]);
    half8 vB = *reinterpret_cast<const half8*>(&vRow[o * 16 + 8]);
    float ag = 0.f, av = 0.f;
#ifdef HAVE_FDOT2
#pragma unroll
    for (int q = 0; q < 4; q++) {
      half2v ga = {gA[2 * q], gA[2 * q + 1]};
      half2v gb = {gB[2 * q], gB[2 * q + 1]};
      half2v va = {vA[2 * q], vA[2 * q + 1]};
      half2v vb = {vB[2 * q], vB[2 * q + 1]};
      ag = __builtin_amdgcn_fdot2(xgh[q], ga, ag, false);
      ag = __builtin_amdgcn_fdot2(xgh[q + 4], gb, ag, false);
      av = __builtin_amdgcn_fdot2(xvh[q], va, av, false);
      av = __builtin_amdgcn_fdot2(xvh[q + 4], vb, av, false);
    }
#else
#pragma unroll
    for (int i = 0; i < 8; i++) {
      ag += xg[i] * (float)gA[i] + xg[i + 8] * (float)gB[i];
      av += xv[i] * (float)vA[i] + xv[i + 8] * (float)vB[i];
    }
#endif
    res[o] = (f16)(fmaxf(ag, 0.f) * av);
  }
  uint4* op = reinterpret_cast<uint4*>(&msg[(size_t)j * 256 + g * 16]);
  op[0] = reinterpret_cast<const uint4*>(res)[0];
  op[1] = reinterpret_cast<const uint4*>(res)[1];
}

// ---------------- glb middle (f16 input, pre-normalized): glin + relu*mul ----------------
template <int DOUT>
__global__ __launch_bounds__(256) void glb_mid_h_kernel(
    const f16* __restrict__ X, const float* __restrict__ gate_w,
    const float* __restrict__ val_w, f16* __restrict__ out) {
  constexpr int RS = DOUT * 16 + 8;
  __shared__ f16 sg[16 * RS];
  __shared__ f16 sv[16 * RS];
  int tid = threadIdx.x;
  for (int i = tid; i < 16 * DOUT * 16; i += 256) {
    int g = i / (DOUT * 16), rem = i % (DOUT * 16);
    sg[g * RS + rem] = (f16)gate_w[i];
    sv[g * RS + rem] = (f16)val_w[i];
  }
  __syncthreads();
  int idx = blockIdx.x * 256 + tid;
  int n = idx >> 4, g = idx & 15;
  half8 x0 = *reinterpret_cast<const half8*>(&X[(size_t)n * 256 + g * 16]);
  half8 x1 = *reinterpret_cast<const half8*>(&X[(size_t)n * 256 + g * 16 + 8]);
#ifdef HAVE_FDOT2
  half2v xh[8];
#pragma unroll
  for (int q = 0; q < 4; q++) {
    xh[q][0] = x0[2 * q]; xh[q][1] = x0[2 * q + 1];
    xh[q + 4][0] = x1[2 * q]; xh[q + 4][1] = x1[2 * q + 1];
  }
#else
  float x[16];
#pragma unroll
  for (int i = 0; i < 8; i++) { x[i] = (float)x0[i]; x[i + 8] = (float)x1[i]; }
#endif
  const f16* gRow = &sg[g * RS];
  const f16* vRow = &sv[g * RS];
  f16 res[DOUT];
#pragma unroll
  for (int o = 0; o < DOUT; o++) {
    half8 gA = *reinterpret_cast<const half8*>(&gRow[o * 16]);
    half8 gB = *reinterpret_cast<const half8*>(&gRow[o * 16 + 8]);
    half8 vA = *reinterpret_cast<const half8*>(&vRow[o * 16]);
    half8 vB = *reinterpret_cast<const half8*>(&vRow[o * 16 + 8]);
    float ag = 0.f, av = 0.f;
#ifdef HAVE_FDOT2
#pragma unroll
    for (int q = 0; q < 4; q++) {
      half2v gq = {gA[2 * q], gA[2 * q + 1]};
      half2v g2 = {gB[2 * q], gB[2 * q + 1]};
      half2v vq = {vA[2 * q], vA[2 * q + 1]};
      half2v v2 = {vB[2 * q], vB[2 * q + 1]};
      ag = __builtin_amdgcn_fdot2(xh[q], gq, ag, false);
      ag = __builtin_amdgcn_fdot2(xh[q + 4], g2, ag, false);
      av = __builtin_amdgcn_fdot2(xh[q], vq, av, false);
      av = __builtin_amdgcn_fdot2(xh[q + 4], v2, av, false);
    }
#else
#pragma unroll
    for (int i = 0; i < 8; i++) {
      ag += x[i] * (float)gA[i] + x[i + 8] * (float)gB[i];
      av += x[i] * (float)vA[i] + x[i + 8] * (float)vB[i];
    }
#endif
    res[o] = (f16)(fmaxf(ag, 0.f) * av);
  }
  f16* op = &out[(size_t)n * (16 * DOUT) + g * DOUT];
#pragma unroll
  for (int q = 0; q < DOUT / 8; q++)
    *reinterpret_cast<half8*>(&op[q * 8]) = *reinterpret_cast<const half8*>(&res[q * 8]);
}

// ---------------- fused VirtMessage ----------------
__global__ __launch_bounds__(256) void virt_fused_kernel(
    const float* __restrict__ h_in, const int* __restrict__ goff,
    const float* __restrict__ preW, const float* __restrict__ preb,
    const float* __restrict__ gateW, const float* __restrict__ valW,
    const float* __restrict__ postW, const float* __restrict__ postb,
    float* __restrict__ h_virt, float* __restrict__ vout) {
  __shared__ float sred[4][256];
  __shared__ float sx[256];
  __shared__ float xx[256];
  __shared__ float vv[512];
  int tid = threadIdx.x, b = blockIdx.x;
  int n0 = goff[b], n1 = goff[b + 1];
  int sub = tid >> 6, cg = tid & 63;
  float a0 = 0.f, a1 = 0.f, a2 = 0.f, a3 = 0.f;
  for (int n = n0 + sub; n < n1; n += 4) {
    float4 x = *reinterpret_cast<const float4*>(&h_in[(size_t)n * 256 + cg * 4]);
    a0 += x.x; a1 += x.y; a2 += x.z; a3 += x.w;
  }
  sred[sub][cg * 4 + 0] = a0;
  sred[sub][cg * 4 + 1] = a1;
  sred[sub][cg * 4 + 2] = a2;
  sred[sub][cg * 4 + 3] = a3;
  __syncthreads();
  float acc = h_virt[(size_t)b * 256 + tid] + sred[0][tid] + sred[1][tid] + sred[2][tid] + sred[3][tid];
  h_virt[(size_t)b * 256 + tid] = acc;
  sx[tid] = acc;
  __syncthreads();
  float dot = preb[tid];
  const float4* wrow = reinterpret_cast<const float4*>(&preW[(size_t)tid * 256]);
  const float4* sx4 = reinterpret_cast<const float4*>(sx);
#pragma unroll 8
  for (int q = 0; q < 64; q++) {
    float4 w = wrow[q];
    float4 s = sx4[q];
    dot += w.x * s.x + w.y * s.y + w.z * s.z + w.w * s.w;
  }
  float s1 = dot, s2 = dot * dot;
#pragma unroll
  for (int o_ = 1; o_ < 16; o_ <<= 1) {
    s1 += __shfl_xor(s1, o_);
    s2 += __shfl_xor(s2, o_);
  }
  float mean = s1 * (1.f / 16.f);
  float var = s2 * (1.f / 16.f) - mean * mean;
  xx[tid] = (dot - mean) * rsqrtf(var + 1e-5f);
  __syncthreads();
#pragma unroll
  for (int rep = 0; rep < 2; rep++) {
    int o = tid + rep * 256;
    int g = o >> 5, o2 = o & 31;
    const float4* gw = reinterpret_cast<const float4*>(&gateW[(size_t)(g * 32 + o2) * 16]);
    const float4* vw = reinterpret_cast<const float4*>(&valW[(size_t)(g * 32 + o2) * 16]);
    const float4* xg4 = reinterpret_cast<const float4*>(&xx[g * 16]);
    float ag = 0.f, av = 0.f;
#pragma unroll
    for (int q = 0; q < 4; q++) {
      float4 wg = gw[q], wv = vw[q], xq = xg4[q];
      ag += wg.x * xq.x + wg.y * xq.y + wg.z * xq.z + wg.w * xq.w;
      av += wv.x * xq.x + wv.y * xq.y + wv.z * xq.z + wv.w * xq.w;
    }
    vv[o] = fmaxf(ag, 0.f) * av;
  }
  __syncthreads();
  float outv = postb[tid];
  const float4* prow = reinterpret_cast<const float4*>(&postW[(size_t)tid * 512]);
  const float4* vv4 = reinterpret_cast<const float4*>(vv);
#pragma unroll 8
  for (int q = 0; q < 128; q++) {
    float4 w = prow[q], s = vv4[q];
    outv += w.x * s.x + w.y * s.y + w.z * s.z + w.w * s.w;
  }
  vout[(size_t)b * 256 + tid] = outv;
}

// ---------------- attention ----------------
// h_att layout: [b][h][head][v] = b*8192 + h*512 + head*16 + v
template <bool FIRST>
__global__ __launch_bounds__(256) void att_graph_kernel(
    const float* __restrict__ xv0, const float* __restrict__ k_w,
    const float* __restrict__ v_w, const int* __restrict__ goff,
    float* __restrict__ h_att, float* __restrict__ xk_sum) {
  __shared__ float kx[8][256];
  __shared__ float vx[8][256];
  __shared__ float rows[8][256];
  const int tid = threadIdx.x;
  const int b = blockIdx.x >> 1, half = blockIdx.x & 1;
  const int p = half * 256 + tid;
  const int g = p >> 5;
  const int headLocal = tid >> 4;
  const int head = p >> 4, h = p & 15;
  float wk[16], wv[16];
#pragma unroll
  for (int i = 0; i < 4; i++) {
    float4 k0 = *reinterpret_cast<const float4*>(&k_w[p * 16 + i * 4]);
    float4 v0 = *reinterpret_cast<const float4*>(&v_w[p * 16 + i * 4]);
    wk[i * 4 + 0] = k0.x; wk[i * 4 + 1] = k0.y; wk[i * 4 + 2] = k0.z; wk[i * 4 + 3] = k0.w;
    wv[i * 4 + 0] = v0.x; wv[i * 4 + 1] = v0.y; wv[i * 4 + 2] = v0.z; wv[i * 4 + 3] = v0.w;
  }
  float hacc[16];
  if (FIRST) {
#pragma unroll
    for (int j = 0; j < 16; j++) hacc[j] = 0.f;
  } else {
    const float* hg = &h_att[(size_t)b * 8192];
#pragma unroll
    for (int j = 0; j < 16; j++) hacc[j] = hg[h * 512 + head * 16 + j];
  }
  float ks = 0.f;
  const int n0 = goff[b], n1 = goff[b + 1];
  float r[8];
#pragma unroll
  for (int nn = 0; nn < 8; nn++) {
    int n = n0 + nn;
    r[nn] = (n < n1) ? xv0[(size_t)n * 256 + tid] : 0.f;
  }
  for (int nbase = n0; nbase < n1; nbase += 8) {
#pragma unroll
    for (int nn = 0; nn < 8; nn++) rows[nn][tid] = r[nn];
    __syncthreads();
#pragma unroll
    for (int nn = 0; nn < 8; nn++) {
      int n = nbase + 8 + nn;
      r[nn] = (n < n1) ? xv0[(size_t)n * 256 + tid] : 0.f;
    }
#pragma unroll
    for (int nn = 0; nn < 8; nn++) {
      const float4* rp = reinterpret_cast<const float4*>(&rows[nn][g * 16]);
      float aK = 0.f, aV = 0.f;
#pragma unroll
      for (int q = 0; q < 4; q++) {
        float4 x0 = rp[q];
#pragma unroll
        for (int t = 0; t < 4; t++) {
          float e0 = (&x0.x)[t];
          aK += e0 * wk[q * 4 + t];
          aV += e0 * wv[q * 4 + t];
        }
      }
      bool valid = (nbase + nn) < n1;
      float ek = valid ? expf(aK * 0.25f) : 0.f;
      kx[nn][tid] = ek;
      vx[nn][tid] = aV;
      ks += ek;
    }
    __syncthreads();
#pragma unroll
    for (int nn = 0; nn < 8; nn++) {
      float kk = kx[nn][tid];
      const float4* vp = reinterpret_cast<const float4*>(&vx[nn][headLocal * 16]);
#pragma unroll
      for (int q = 0; q < 4; q++) {
        float4 vq = vp[q];
        hacc[q * 4 + 0] += kk * vq.x;
        hacc[q * 4 + 1] += kk * vq.y;
        hacc[q * 4 + 2] += kk * vq.z;
        hacc[q * 4 + 3] += kk * vq.w;
      }
    }
    __syncthreads();
  }
  float* hgo = &h_att[(size_t)b * 8192];
#pragma unroll
  for (int j = 0; j < 16; j++) hgo[h * 512 + head * 16 + j] = hacc[j];
  xk_sum[(size_t)b * 512 + p] = ks;
}

// Per-graph att_out
__global__ __launch_bounds__(256) void att_out_kernel(
    const float* __restrict__ xv0, const float* __restrict__ q_w,
    const float* __restrict__ xk_sum, const float* __restrict__ h_att,
    const int* __restrict__ goff, f16* __restrict__ out) {
  __shared__ float sqw[16 * 260];
  __shared__ float hat[16 * 644];
  int tid = threadIdx.x, b = blockIdx.x;
  for (int i = tid; i < 8192; i += 256) {
    int g = i >> 9, rem = i & 511;
    sqw[g * 260 + rem] = q_w[i];
  }
  for (int i = tid; i < 8192; i += 256) {
    int h = i >> 9, rem = i & 511;
    int head = rem >> 4, v = rem & 15;
    hat[h * 644 + head * 20 + v] = h_att[(size_t)b * 8192 + i];
  }
  __syncthreads();
  int n0 = goff[b], n1 = goff[b + 1];
  int nl = tid >> 5, head = tid & 31;
  int g = head >> 1, j = head & 1;
  const float* ks = &xk_sum[(size_t)b * 512 + head * 16];
  for (int nbase = n0; nbase < n1; nbase += 8) {
    int n = nbase + nl;
    if (n >= n1) continue;
    float x[16];
    const float4* xp4 = reinterpret_cast<const float4*>(&xv0[(size_t)n * 256 + g * 16]);
#pragma unroll
    for (int q = 0; q < 4; q++) {
      float4 xq = xp4[q];
#pragma unroll
      for (int t = 0; t < 4; t++) x[q * 4 + t] = (&xq.x)[t];
    }
    float qv[16];
    float denom = 0.f;
#pragma unroll
    for (int h = 0; h < 16; h++) {
      const float4* wp = reinterpret_cast<const float4*>(&sqw[g * 260 + (j * 16 + h) * 16]);
      float a = 0.f;
#pragma unroll
      for (int q = 0; q < 4; q++) {
        float4 wq = wp[q];
#pragma unroll
        for (int t = 0; t < 4; t++) a += x[q * 4 + t] * (&wq.x)[t];
      }
      float e = expf(a * 0.25f);
      qv[h] = e;
      denom += e * ks[h];
    }
    float inv = 1.f / denom;
    float acc[16] = {0.f, 0.f, 0.f, 0.f, 0.f, 0.f, 0.f, 0.f,
                     0.f, 0.f, 0.f, 0.f, 0.f, 0.f, 0.f, 0.f};
#pragma unroll
    for (int h = 0; h < 16; h++) {
      float qh = qv[h];
      const float4* hp = reinterpret_cast<const float4*>(&hat[h * 644 + head * 20]);
#pragma unroll
      for (int q = 0; q < 4; q++) {
        float4 vq = hp[q];
        acc[q * 4 + 0] += qh * vq.x;
        acc[q * 4 + 1] += qh * vq.y;
        acc[q * 4 + 2] += qh * vq.z;
        acc[q * 4 + 3] += qh * vq.w;
      }
    }
    f16 res[16];
#pragma unroll
    for (int v = 0; v < 16; v++) res[v] = (f16)(acc[v] * inv);
    uint4* op = reinterpret_cast<uint4*>(&out[(size_t)n * 512 + head * 16]);
    op[0] = reinterpret_cast<const uint4*>(res)[0];
    op[1] = reinterpret_cast<const uint4*>(res)[1];
  }
}

// ---------------- host driver ----------------

extern "C" void kernel_launch(void* const* d_in, const int* in_sizes, int n_in,
                              void* d_out, int out_size, void* d_ws, size_t ws_size,
                              hipStream_t stream) {
  const int* x_feat = (const int*)d_in[0];
  const int* eidx = (const int*)d_in[1];
  const int* eattr = (const int*)d_in[2];
  const int* batch = (const int*)d_in[3];
  const float* edist = (const float*)d_in[5];
  const float* atom_emb = (const float*)d_in[6];
  const float* bond2d = (const float*)d_in[7];
  const float* gmeans = (const float*)d_in[8];
  const float* gstds = (const float*)d_in[9];
  const float* attn_w = (const float*)d_in[10];
  const float* attn_b = (const float*)d_in[11];
  const float* scale_both = (const float*)d_in[12];
  const float* conv_bond_emb = (const float*)d_in[13];
  const float* conv_pre_w = (const float*)d_in[14];
  const float* conv_gate_w = (const float*)d_in[15];
  const float* conv_val_w = (const float*)d_in[16];
  const float* conv_post_w = (const float*)d_in[17];
  const float* conv_post_b = (const float*)d_in[18];
  const float* conv_scale = (const float*)d_in[19];
  const float* virt_pre_w = (const float*)d_in[20];
  const float* virt_pre_b = (const float*)d_in[21];
  const float* virt_gate_w = (const float*)d_in[22];
  const float* virt_val_w = (const float*)d_in[23];
  const float* virt_post_w = (const float*)d_in[24];
  const float* virt_post_b = (const float*)d_in[25];
  const float* virt_scale = (const float*)d_in[26];
  const float* att_pre_w = (const float*)d_in[27];
  const float* att_pre_b = (const float*)d_in[28];
  const float* att_q_w = (const float*)d_in[29];
  const float* att_k_w = (const float*)d_in[30];
  const float* att_v_w = (const float*)d_in[31];
  const float* att_post_w = (const float*)d_in[32];
  const float* att_post_b = (const float*)d_in[33];
  const float* att_scale = (const float*)d_in[34];
  const float* main_pre_w = (const float*)d_in[35];
  const float* main_pre_b = (const float*)d_in[36];
  const float* main_gate_w = (const float*)d_in[37];
  const float* main_val_w = (const float*)d_in[38];
  const float* main_post_w = (const float*)d_in[39];
  const float* main_post_b = (const float*)d_in[40];

  const int* src = eidx;
  const int* dst = eidx + EE;

  float* ws = (float*)d_ws;
  float* h_in = ws;
  float* x_out = ws + ND;
  float* nodeA = ws + 2 * ND;
  f16* h_inH = (f16*)(ws + 3 * ND);
  f16* xrawH = (f16*)(ws + 3 * ND + ND / 2);
  f16* hTmp = (f16*)(ws + 4 * ND);
  f16* gnH = (f16*)(ws + 4 * ND + ND / 2);
  f16* msgH = (f16*)(ws + 5 * ND);            // 3*ND halfs
  float* sm = ws + 7 * ND;
  f16* hW = (f16*)sm;                          // weights fp16 pool
  float* h_virt = sm + 1179648;
  float* h_att = h_virt + 65536;
  float* xk_sum = h_att + 2097152;
  float* vout = xk_sum + 131072;               // B*256
  int* cnt = (int*)(vout + 65536);
  int* deg = cnt + NN;
  int* goff = deg + NN;
  int* off = goff + BB + 1;
  int* cursor = off + NN + 1;
  int* elist = cursor + NN;
  int* ea_s = elist + EE;
  int* src_s = ea_s + 3 * EE;
  int* dst_s = src_s + EE;
  float* ed_s = (float*)(dst_s + EE);

  f16* wCpre = hW;
  f16* wCpost = hW + 524288;
  f16* wApre = hW + 1048576;
  f16* wApost = hW + 1179648;
  f16* wMpre = hW + 1441792;
  f16* wMpost = hW + 1572864;

  // one dispatch converts all six weight tensors to fp16
  cvt6_kernel<<<491520 / 256, 256, 0, stream>>>(
      conv_pre_w, conv_post_w, att_pre_w, att_post_w, main_pre_w, main_post_w,
      wCpre, wCpost, wApre, wApost, wMpre, wMpost);

  // degree + graph offsets + CSR + gathered edge data
  (void)hipMemsetAsync(cnt, 0, NN * sizeof(int), stream);
  count_deg_kernel<<<EE / 256, 256, 0, stream>>>(dst, cnt, EE);
  clip_deg_kernel<<<NN / 256, 256, 0, stream>>>(cnt, deg, NN);
  goff_kernel<<<(NN + 256) / 256, 256, 0, stream>>>(batch, goff, NN, BB);
  scan_off_kernel<<<1, 256, 0, stream>>>(cnt, off);
  copy_i_kernel<<<NN / 256, 256, 0, stream>>>(off, cursor, NN);
  fill_elist_kernel<<<EE / 256, 256, 0, stream>>>(dst, cursor, elist, EE);
  gather_edges_kernel<<<EE / 256, 256, 0, stream>>>(elist, eattr, src, dst, edist,
                                                    ea_s, src_s, dst_s, ed_s);

  // initial node features
  edge_feat_kernel<<<EE / 4, 256, 0, stream>>>(ea_s, ed_s, bond2d, gmeans, gstds,
                                               attn_w, attn_b, msgH);
  seg_reduce_kernel<float><<<NN / 4, 256, 0, stream>>>(msgH, off, x_out);
  atom_finish_kernel<<<NN * 64 / 256, 256, 0, stream>>>(x_feat, atom_emb, scale_both, deg,
                                                        x_out, h_in, h_inH);
  (void)hipMemsetAsync(h_virt, 0, 65536 * 4, stream);

  const dim3 gN(NN / 64, 4);
  const int n4 = (int)(ND / 4);

  for (int l = 0; l < 2; l++) {
    // ---- ConvMessage ----
    const f16* curH = h_inH;
    for (int k = 0; k < 4; k++) {
      if (k == 2) {
        add3h_kernel<<<n4 / 256, 256, 0, stream>>>(xrawH, h_in, x_out, n4);
        curH = xrawH;
      }
      size_t lk = (size_t)(l * 4 + k);
      hgemm_kernel<0><<<gN, 256, 0, stream>>>(curH, wCpre + lk * 65536, nullptr, nullptr,
                                              nullptr, nullptr, nullptr, nullptr, hTmp,
                                              nullptr, nullptr, nullptr, 256);
      conv_edge_kernel<<<EE * 16 / 256, 256, 0, stream>>>(
          hTmp, ea_s, src_s, dst_s, conv_bond_emb + lk * 6144,
          conv_gate_w + lk * 4096, conv_val_w + lk * 4096, msgH);
      seg_reduce_kernel<f16><<<NN / 4, 256, 0, stream>>>(msgH, off, gnH);
      if (k == 0 || k == 2)
        hgemm_kernel<5><<<gN, 256, 0, stream>>>(gnH, wCpost + lk * 65536,
                                                conv_post_b + lk * 256, conv_scale + lk * 1024,
                                                cnt, deg, nullptr, x_out, xrawH,
                                                nullptr, nullptr, nullptr, 256);
      else
        hgemm_kernel<4><<<gN, 256, 0, stream>>>(gnH, wCpost + lk * 65536,
                                                conv_post_b + lk * 256, conv_scale + lk * 1024,
                                                cnt, deg, nullptr, x_out, xrawH,
                                                nullptr, nullptr, nullptr, 256);
      curH = xrawH;
    }
    // h_out = h_in + x_out folded into MODE 7 epilogue below.

    // ---- VirtMessage (fused) ----
    virt_fused_kernel<<<BB, 256, 0, stream>>>(
        h_in, goff, virt_pre_w + (size_t)l * 65536, virt_pre_b + (size_t)l * 256,
        virt_gate_w + (size_t)l * 8192, virt_val_w + (size_t)l * 8192,
        virt_post_w + (size_t)l * 131072, virt_post_b + (size_t)l * 256, h_virt, vout);

    // ---- AttMessage ----
    hgemm_kernel<6><<<gN, 256, 0, stream>>>(h_inH, wApre + (size_t)l * 65536,
                                            att_pre_b + (size_t)l * 256, nullptr, nullptr,
                                            nullptr, nodeA, nullptr, nullptr,
                                            nullptr, nullptr, nullptr, 256);
    if (l == 0)
      att_graph_kernel<true><<<BB * 2, 256, 0, stream>>>(
          nodeA, att_k_w + (size_t)l * 8192, att_v_w + (size_t)l * 8192, goff, h_att, xk_sum);
    else
      att_graph_kernel<false><<<BB * 2, 256, 0, stream>>>(
          nodeA, att_k_w + (size_t)l * 8192, att_v_w + (size_t)l * 8192, goff, h_att, xk_sum);
    att_out_kernel<<<BB, 256, 0, stream>>>(
        nodeA, att_q_w + (size_t)l * 8192, xk_sum, h_att, goff, msgH);
    // hTmp = f16(h_in + x_out + exp(vs)*vout[batch] + exp(as)*attpost)
    hgemm_kernel<7><<<gN, 256, 0, stream>>>(msgH, wApost + (size_t)l * 131072,
                                            att_post_b + (size_t)l * 256,
                                            att_scale + (size_t)l * 256, nullptr, nullptr,
                                            h_in, x_out, hTmp,
                                            virt_scale + (size_t)l * 256, vout, batch, 512);

    // ---- main gated block ----
    hgemm_kernel<6><<<gN, 256, 0, stream>>>(hTmp, wMpre + (size_t)l * 65536,
                                            main_pre_b + (size_t)l * 256, nullptr, nullptr,
                                            nullptr, nullptr, nullptr, gnH,
                                            nullptr, nullptr, nullptr, 256);
    glb_mid_h_kernel<48><<<NN * 16 / 256, 256, 0, stream>>>(
        gnH, main_gate_w + (size_t)l * 12288, main_val_w + (size_t)l * 12288, msgH);
    float* hdst = (l == 1) ? (float*)d_out : h_in;
    f16* hdstH = (l == 1) ? nullptr : h_inH;
    hgemm_kernel<0><<<gN, 256, 0, stream>>>(msgH, wMpost + (size_t)l * 196608,
                                            main_post_b + (size_t)l * 256, nullptr, nullptr,
                                            nullptr, hdst, nullptr, hdstH,
                                            nullptr, nullptr, nullptr, 768);
  }
}